// Round 2
// baseline (6386.591 us; speedup 1.0000x reference)
//
#include <hip/hip_runtime.h>
#include <math.h>

#define SS   2048
#define HH   2048
#define NH_  32
#define NKV_ 8
#define HD_  64
#define QKVO 3072     // (32 + 2*8) * 64
#define MTOK 4096     // B * S

// ---------------- sum |w| reduction ----------------
__global__ __launch_bounds__(256) void absum_kernel(const float* __restrict__ w,
                                                    float* __restrict__ out, int n) {
    __shared__ float red[256];
    int tid = threadIdx.x;
    float acc = 0.f;
    for (int i = blockIdx.x * 256 + tid; i < n; i += gridDim.x * 256)
        acc += fabsf(w[i]);
    red[tid] = acc;
    __syncthreads();
    for (int s = 128; s > 0; s >>= 1) {
        if (tid < s) red[tid] += red[tid + s];
        __syncthreads();
    }
    if (tid == 0) atomicAdd(out, red[0]);
}

// ---------------- ternary weight quant ----------------
__global__ __launch_bounds__(256) void wquant_kernel(const float* __restrict__ w,
                                                     float* __restrict__ wq,
                                                     const float* __restrict__ sum,
                                                     float inv_n, int n) {
    float mean = fmaxf(sum[0] * inv_n, 1e-5f);
    float wsc = 1.f / mean;
    for (int i = blockIdx.x * 256 + threadIdx.x; i < n; i += gridDim.x * 256) {
        float q = rintf(w[i] * wsc);
        wq[i] = fminf(fmaxf(q, -1.f), 1.f);
    }
}

// ---------------- RMSNorm + activation quant (one block per row, H=2048) ----------------
__global__ __launch_bounds__(256) void rmsq_kernel(const float* __restrict__ x,
                                                   const float* __restrict__ wn,
                                                   float* __restrict__ xq,
                                                   float* __restrict__ xsc) {
    __shared__ float red[256];
    int tid = threadIdx.x;
    const float* xr = x + (size_t)blockIdx.x * HH;
    float4 a = ((const float4*)xr)[tid];
    float4 b = ((const float4*)xr)[tid + 256];
    float s2 = a.x*a.x + a.y*a.y + a.z*a.z + a.w*a.w
             + b.x*b.x + b.y*b.y + b.z*b.z + b.w*b.w;
    red[tid] = s2;
    __syncthreads();
    for (int s = 128; s > 0; s >>= 1) { if (tid < s) red[tid] += red[tid + s]; __syncthreads(); }
    float r = rsqrtf(red[0] * (1.f / HH) + 1e-5f);
    __syncthreads();
    float4 wa = ((const float4*)wn)[tid];
    float4 wb = ((const float4*)wn)[tid + 256];
    float4 na, nb;
    na.x = a.x * r * wa.x; na.y = a.y * r * wa.y; na.z = a.z * r * wa.z; na.w = a.w * r * wa.w;
    nb.x = b.x * r * wb.x; nb.y = b.y * r * wb.y; nb.z = b.z * r * wb.z; nb.w = b.w * r * wb.w;
    float am = fabsf(na.x);
    am = fmaxf(am, fabsf(na.y)); am = fmaxf(am, fabsf(na.z)); am = fmaxf(am, fabsf(na.w));
    am = fmaxf(am, fabsf(nb.x)); am = fmaxf(am, fabsf(nb.y));
    am = fmaxf(am, fabsf(nb.z)); am = fmaxf(am, fabsf(nb.w));
    red[tid] = am;
    __syncthreads();
    for (int s = 128; s > 0; s >>= 1) { if (tid < s) red[tid] = fmaxf(red[tid], red[tid + s]); __syncthreads(); }
    float amax = fmaxf(red[0], 1e-5f);
    float xs = 127.f / amax;
    if (tid == 0) xsc[blockIdx.x] = amax * (1.f / 127.f);
    float* qr = xq + (size_t)blockIdx.x * HH;
    float4 qa, qb;
    qa.x = fminf(fmaxf(rintf(na.x * xs), -128.f), 127.f);
    qa.y = fminf(fmaxf(rintf(na.y * xs), -128.f), 127.f);
    qa.z = fminf(fmaxf(rintf(na.z * xs), -128.f), 127.f);
    qa.w = fminf(fmaxf(rintf(na.w * xs), -128.f), 127.f);
    qb.x = fminf(fmaxf(rintf(nb.x * xs), -128.f), 127.f);
    qb.y = fminf(fmaxf(rintf(nb.y * xs), -128.f), 127.f);
    qb.z = fminf(fmaxf(rintf(nb.z * xs), -128.f), 127.f);
    qb.w = fminf(fmaxf(rintf(nb.w * xs), -128.f), 127.f);
    ((float4*)qr)[tid] = qa;
    ((float4*)qr)[tid + 256] = qb;
}

// ---------------- row absmax quant (attention output, H=2048) ----------------
__global__ __launch_bounds__(256) void rowq_kernel(const float* __restrict__ x,
                                                   float* __restrict__ xq,
                                                   float* __restrict__ xsc) {
    __shared__ float red[256];
    int tid = threadIdx.x;
    const float* xr = x + (size_t)blockIdx.x * HH;
    float4 a = ((const float4*)xr)[tid];
    float4 b = ((const float4*)xr)[tid + 256];
    float am = fabsf(a.x);
    am = fmaxf(am, fabsf(a.y)); am = fmaxf(am, fabsf(a.z)); am = fmaxf(am, fabsf(a.w));
    am = fmaxf(am, fabsf(b.x)); am = fmaxf(am, fabsf(b.y));
    am = fmaxf(am, fabsf(b.z)); am = fmaxf(am, fabsf(b.w));
    red[tid] = am;
    __syncthreads();
    for (int s = 128; s > 0; s >>= 1) { if (tid < s) red[tid] = fmaxf(red[tid], red[tid + s]); __syncthreads(); }
    float amax = fmaxf(red[0], 1e-5f);
    float xs = 127.f / amax;
    if (tid == 0) xsc[blockIdx.x] = amax * (1.f / 127.f);
    float* qr = xq + (size_t)blockIdx.x * HH;
    float4 qa, qb;
    qa.x = fminf(fmaxf(rintf(a.x * xs), -128.f), 127.f);
    qa.y = fminf(fmaxf(rintf(a.y * xs), -128.f), 127.f);
    qa.z = fminf(fmaxf(rintf(a.z * xs), -128.f), 127.f);
    qa.w = fminf(fmaxf(rintf(a.w * xs), -128.f), 127.f);
    qb.x = fminf(fmaxf(rintf(b.x * xs), -128.f), 127.f);
    qb.y = fminf(fmaxf(rintf(b.y * xs), -128.f), 127.f);
    qb.z = fminf(fmaxf(rintf(b.z * xs), -128.f), 127.f);
    qb.w = fminf(fmaxf(rintf(b.w * xs), -128.f), 127.f);
    ((float4*)qr)[tid] = qa;
    ((float4*)qr)[tid + 256] = qb;
}

// ---------------- tiled GEMM: C[M,N] = A[M,K] * B[N,K]^T, scaled epilogue ----------------
__global__ __launch_bounds__(256) void gemm_kernel(const float* __restrict__ A,
                                                   const float* __restrict__ B,
                                                   float* __restrict__ C,
                                                   const float* __restrict__ rsc,
                                                   const float* __restrict__ wsum,
                                                   float inv_n, int N, int K) {
    __shared__ float As[16][68];
    __shared__ float Bs[16][68];
    int tid = threadIdx.x;
    int tx = tid & 15, ty = tid >> 4;
    int m0 = blockIdx.y << 6, n0 = blockIdx.x << 6;
    int lr = tid >> 4, lc = tid & 15;
    float acc[4][4] = {{0.f}};
    for (int k0 = 0; k0 < K; k0 += 16) {
        #pragma unroll
        for (int i = 0; i < 4; ++i) {
            As[lc][lr + 16 * i] = A[(size_t)(m0 + lr + 16 * i) * K + k0 + lc];
            Bs[lc][lr + 16 * i] = B[(size_t)(n0 + lr + 16 * i) * K + k0 + lc];
        }
        __syncthreads();
        #pragma unroll
        for (int kk = 0; kk < 16; ++kk) {
            float a0 = As[kk][ty * 4 + 0], a1 = As[kk][ty * 4 + 1];
            float a2 = As[kk][ty * 4 + 2], a3 = As[kk][ty * 4 + 3];
            float b0 = Bs[kk][tx * 4 + 0], b1 = Bs[kk][tx * 4 + 1];
            float b2 = Bs[kk][tx * 4 + 2], b3 = Bs[kk][tx * 4 + 3];
            acc[0][0] = fmaf(a0, b0, acc[0][0]); acc[0][1] = fmaf(a0, b1, acc[0][1]);
            acc[0][2] = fmaf(a0, b2, acc[0][2]); acc[0][3] = fmaf(a0, b3, acc[0][3]);
            acc[1][0] = fmaf(a1, b0, acc[1][0]); acc[1][1] = fmaf(a1, b1, acc[1][1]);
            acc[1][2] = fmaf(a1, b2, acc[1][2]); acc[1][3] = fmaf(a1, b3, acc[1][3]);
            acc[2][0] = fmaf(a2, b0, acc[2][0]); acc[2][1] = fmaf(a2, b1, acc[2][1]);
            acc[2][2] = fmaf(a2, b2, acc[2][2]); acc[2][3] = fmaf(a2, b3, acc[2][3]);
            acc[3][0] = fmaf(a3, b0, acc[3][0]); acc[3][1] = fmaf(a3, b1, acc[3][1]);
            acc[3][2] = fmaf(a3, b2, acc[3][2]); acc[3][3] = fmaf(a3, b3, acc[3][3]);
        }
        __syncthreads();
    }
    float wsc = fmaxf(wsum[0] * inv_n, 1e-5f);
    #pragma unroll
    for (int i = 0; i < 4; ++i) {
        int m = m0 + ty * 4 + i;
        float s = rsc[m] * wsc;
        #pragma unroll
        for (int j = 0; j < 4; ++j)
            C[(size_t)m * N + n0 + tx * 4 + j] = acc[i][j] * s;
    }
}

// ---------------- RoPE table: tab[s*64 + d] = cos, tab[s*64+32+d] = sin ----------------
__global__ __launch_bounds__(256) void rope_table_kernel(float* __restrict__ tab) {
    int i = blockIdx.x * 256 + threadIdx.x;     // S*32 threads
    int sp = i >> 5, d = i & 31;
    float inv = (float)pow(10000.0, -(double)d / 32.0);
    float ang = (float)sp * inv;
    tab[sp * 64 + d]      = cosf(ang);
    tab[sp * 64 + 32 + d] = sinf(ang);
}

// ---------------- RoPE apply (in-place on qkv; q heads 0..31, k heads 32..39) ----------------
__global__ __launch_bounds__(256) void rope_apply_kernel(float* __restrict__ qkv,
                                                         const float* __restrict__ tab) {
    int i = blockIdx.x * 256 + threadIdx.x;     // MTOK*40*32 threads
    int d = i & 31;
    int hh = (i >> 5) % 40;
    int row = i / 1280;
    int sp = row & (SS - 1);
    size_t base = (size_t)row * QKVO + (hh < 32 ? hh * 64 : HH + (hh - 32) * 64);
    float c = tab[sp * 64 + d], sn = tab[sp * 64 + 32 + d];
    float xr = qkv[base + d], xi = qkv[base + d + 32];
    qkv[base + d]      = xr * c - xi * sn;
    qkv[base + d + 32] = xr * sn + xi * c;
}

// ---------------- attention: one wave per (b, h, s) query row ----------------
__global__ __launch_bounds__(256) void attn_kernel(const float* __restrict__ qkv,
                                                   float* __restrict__ outp) {
    __shared__ float sc[4][SS];
    __shared__ float sq[4][64];
    int wave = threadIdx.x >> 6;
    int lane = threadIdx.x & 63;
    int gw = blockIdx.x * 4 + wave;
    int s = gw & (SS - 1);
    int bh = gw >> 11;
    int h = bh & (NH_ - 1);
    int b = bh >> 5;
    int kh = h >> 2;                             // G = 4
    const float* qrow = qkv + ((size_t)(b * SS + s)) * QKVO + h * HD_;
    const float* Kb = qkv + (size_t)b * SS * QKVO + HH + kh * HD_;
    const float* Vb = Kb + NKV_ * HD_;
    sq[wave][lane] = qrow[lane] * 0.125f;        // 1/sqrt(64) folded into q
    __syncthreads();
    // pass A: scores -> LDS, track max
    float mloc = -INFINITY;
    for (int t0 = 0; t0 <= s; t0 += 64) {
        int t = t0 + lane;
        if (t <= s) {
            const float* kr = Kb + (size_t)t * QKVO;
            float acc = 0.f;
            #pragma unroll
            for (int d = 0; d < 64; d += 4) {
                float4 k4 = *(const float4*)(kr + d);
                acc = fmaf(sq[wave][d + 0], k4.x, acc);
                acc = fmaf(sq[wave][d + 1], k4.y, acc);
                acc = fmaf(sq[wave][d + 2], k4.z, acc);
                acc = fmaf(sq[wave][d + 3], k4.w, acc);
            }
            sc[wave][t] = acc;
            mloc = fmaxf(mloc, acc);
        }
    }
    #pragma unroll
    for (int off = 32; off > 0; off >>= 1)
        mloc = fmaxf(mloc, __shfl_xor(mloc, off, 64));
    __syncthreads();
    // pass B: lane owns output dim d = lane; coalesced V reads; l identical across lanes
    float l = 0.f, oacc = 0.f;
    const float* vcol = Vb + lane;
    for (int t = 0; t <= s; ++t) {
        float p = __expf(sc[wave][t] - mloc);
        l += p;
        oacc = fmaf(p, vcol[(size_t)t * QKVO], oacc);
    }
    outp[((size_t)(b * SS + s)) * HH + h * HD_ + lane] = oacc / l;
}

extern "C" void kernel_launch(void* const* d_in, const int* in_sizes, int n_in,
                              void* d_out, int out_size, void* d_ws, size_t ws_size,
                              hipStream_t stream) {
    const float* x      = (const float*)d_in[0];
    const float* w_norm = (const float*)d_in[1];
    const float* w_qkv  = (const float*)d_in[2];
    const float* w_out  = (const float*)d_in[3];
    float* out = (float*)d_out;
    char* ws = (char*)d_ws;

    float* scal  = (float*)(ws + 0);          // [0]=sum|w_qkv|, [1]=sum|w_out|
    float* rope  = (float*)(ws + 64);         // 2048*64 floats
    float* xq    = (float*)(ws + 524352);     // 4096*2048 floats (quantized acts, reused)
    float* xsc   = (float*)(ws + 34078784);   // 4096 floats (row scales)
    float* wq1   = (float*)(ws + 34095168);   // 3072*2048 floats
    float* wq2   = (float*)(ws + 59260992);   // 2048*2048 floats
    float* qkv   = (float*)(ws + 76038208);   // 4096*3072 floats
    float* attno = (float*)(ws + 126369856);  // 4096*2048 floats

    hipMemsetAsync(scal, 0, 64, stream);
    absum_kernel<<<2048, 256, 0, stream>>>(w_qkv, scal + 0, QKVO * HH);
    absum_kernel<<<2048, 256, 0, stream>>>(w_out, scal + 1, HH * HH);
    wquant_kernel<<<8192, 256, 0, stream>>>(w_qkv, wq1, scal + 0, 1.0f / 6291456.0f, QKVO * HH);
    wquant_kernel<<<8192, 256, 0, stream>>>(w_out, wq2, scal + 1, 1.0f / 4194304.0f, HH * HH);
    rmsq_kernel<<<MTOK, 256, 0, stream>>>(x, w_norm, xq, xsc);
    gemm_kernel<<<dim3(QKVO / 64, MTOK / 64), 256, 0, stream>>>(xq, wq1, qkv, xsc, scal + 0,
                                                                1.0f / 6291456.0f, QKVO, HH);
    rope_table_kernel<<<SS * 32 / 256, 256, 0, stream>>>(rope);
    rope_apply_kernel<<<MTOK * 40 * 32 / 256, 256, 0, stream>>>(qkv, rope);
    attn_kernel<<<MTOK * NH_ / 4, 256, 0, stream>>>(qkv, attno);
    rowq_kernel<<<MTOK, 256, 0, stream>>>(attno, xq, xsc);
    gemm_kernel<<<dim3(HH / 64, MTOK / 64), 256, 0, stream>>>(xq, wq2, out, xsc, scal + 1,
                                                              1.0f / 4194304.0f, HH, HH);
}

// Round 3
// 2324.754 us; speedup vs baseline: 2.7472x; 2.7472x over previous
//
#include <hip/hip_runtime.h>
#include <math.h>

#define SS   2048
#define HH   2048
#define NH_  32
#define NKV_ 8
#define HD_  64
#define QKVO 3072     // (32 + 2*8) * 64
#define MTOK 4096     // B * S

// ---------------- sum |w| reduction ----------------
__global__ __launch_bounds__(256) void absum_kernel(const float* __restrict__ w,
                                                    float* __restrict__ out, int n) {
    __shared__ float red[256];
    int tid = threadIdx.x;
    float acc = 0.f;
    for (int i = blockIdx.x * 256 + tid; i < n; i += gridDim.x * 256)
        acc += fabsf(w[i]);
    red[tid] = acc;
    __syncthreads();
    for (int s = 128; s > 0; s >>= 1) {
        if (tid < s) red[tid] += red[tid + s];
        __syncthreads();
    }
    if (tid == 0) atomicAdd(out, red[0]);
}

// ---------------- ternary weight quant ----------------
__global__ __launch_bounds__(256) void wquant_kernel(const float* __restrict__ w,
                                                     float* __restrict__ wq,
                                                     const float* __restrict__ sum,
                                                     float inv_n, int n) {
    float mean = fmaxf(sum[0] * inv_n, 1e-5f);
    float wsc = 1.f / mean;
    for (int i = blockIdx.x * 256 + threadIdx.x; i < n; i += gridDim.x * 256) {
        float q = rintf(w[i] * wsc);
        wq[i] = fminf(fmaxf(q, -1.f), 1.f);
    }
}

// ---------------- RMSNorm + activation quant (one block per row, H=2048) ----------------
__global__ __launch_bounds__(256) void rmsq_kernel(const float* __restrict__ x,
                                                   const float* __restrict__ wn,
                                                   float* __restrict__ xq,
                                                   float* __restrict__ xsc) {
    __shared__ float red[256];
    int tid = threadIdx.x;
    const float* xr = x + (size_t)blockIdx.x * HH;
    float4 a = ((const float4*)xr)[tid];
    float4 b = ((const float4*)xr)[tid + 256];
    float s2 = a.x*a.x + a.y*a.y + a.z*a.z + a.w*a.w
             + b.x*b.x + b.y*b.y + b.z*b.z + b.w*b.w;
    red[tid] = s2;
    __syncthreads();
    for (int s = 128; s > 0; s >>= 1) { if (tid < s) red[tid] += red[tid + s]; __syncthreads(); }
    float r = rsqrtf(red[0] * (1.f / HH) + 1e-5f);
    __syncthreads();
    float4 wa = ((const float4*)wn)[tid];
    float4 wb = ((const float4*)wn)[tid + 256];
    float4 na, nb;
    na.x = a.x * r * wa.x; na.y = a.y * r * wa.y; na.z = a.z * r * wa.z; na.w = a.w * r * wa.w;
    nb.x = b.x * r * wb.x; nb.y = b.y * r * wb.y; nb.z = b.z * r * wb.z; nb.w = b.w * r * wb.w;
    float am = fabsf(na.x);
    am = fmaxf(am, fabsf(na.y)); am = fmaxf(am, fabsf(na.z)); am = fmaxf(am, fabsf(na.w));
    am = fmaxf(am, fabsf(nb.x)); am = fmaxf(am, fabsf(nb.y));
    am = fmaxf(am, fabsf(nb.z)); am = fmaxf(am, fabsf(nb.w));
    red[tid] = am;
    __syncthreads();
    for (int s = 128; s > 0; s >>= 1) { if (tid < s) red[tid] = fmaxf(red[tid], red[tid + s]); __syncthreads(); }
    float amax = fmaxf(red[0], 1e-5f);
    float xs = 127.f / amax;
    if (tid == 0) xsc[blockIdx.x] = amax * (1.f / 127.f);
    float* qr = xq + (size_t)blockIdx.x * HH;
    float4 qa, qb;
    qa.x = fminf(fmaxf(rintf(na.x * xs), -128.f), 127.f);
    qa.y = fminf(fmaxf(rintf(na.y * xs), -128.f), 127.f);
    qa.z = fminf(fmaxf(rintf(na.z * xs), -128.f), 127.f);
    qa.w = fminf(fmaxf(rintf(na.w * xs), -128.f), 127.f);
    qb.x = fminf(fmaxf(rintf(nb.x * xs), -128.f), 127.f);
    qb.y = fminf(fmaxf(rintf(nb.y * xs), -128.f), 127.f);
    qb.z = fminf(fmaxf(rintf(nb.z * xs), -128.f), 127.f);
    qb.w = fminf(fmaxf(rintf(nb.w * xs), -128.f), 127.f);
    ((float4*)qr)[tid] = qa;
    ((float4*)qr)[tid + 256] = qb;
}

// ---------------- row absmax quant (attention output, H=2048) ----------------
__global__ __launch_bounds__(256) void rowq_kernel(const float* __restrict__ x,
                                                   float* __restrict__ xq,
                                                   float* __restrict__ xsc) {
    __shared__ float red[256];
    int tid = threadIdx.x;
    const float* xr = x + (size_t)blockIdx.x * HH;
    float4 a = ((const float4*)xr)[tid];
    float4 b = ((const float4*)xr)[tid + 256];
    float am = fabsf(a.x);
    am = fmaxf(am, fabsf(a.y)); am = fmaxf(am, fabsf(a.z)); am = fmaxf(am, fabsf(a.w));
    am = fmaxf(am, fabsf(b.x)); am = fmaxf(am, fabsf(b.y));
    am = fmaxf(am, fabsf(b.z)); am = fmaxf(am, fabsf(b.w));
    red[tid] = am;
    __syncthreads();
    for (int s = 128; s > 0; s >>= 1) { if (tid < s) red[tid] = fmaxf(red[tid], red[tid + s]); __syncthreads(); }
    float amax = fmaxf(red[0], 1e-5f);
    float xs = 127.f / amax;
    if (tid == 0) xsc[blockIdx.x] = amax * (1.f / 127.f);
    float* qr = xq + (size_t)blockIdx.x * HH;
    float4 qa, qb;
    qa.x = fminf(fmaxf(rintf(a.x * xs), -128.f), 127.f);
    qa.y = fminf(fmaxf(rintf(a.y * xs), -128.f), 127.f);
    qa.z = fminf(fmaxf(rintf(a.z * xs), -128.f), 127.f);
    qa.w = fminf(fmaxf(rintf(a.w * xs), -128.f), 127.f);
    qb.x = fminf(fmaxf(rintf(b.x * xs), -128.f), 127.f);
    qb.y = fminf(fmaxf(rintf(b.y * xs), -128.f), 127.f);
    qb.z = fminf(fmaxf(rintf(b.z * xs), -128.f), 127.f);
    qb.w = fminf(fmaxf(rintf(b.w * xs), -128.f), 127.f);
    ((float4*)qr)[tid] = qa;
    ((float4*)qr)[tid + 256] = qb;
}

// ---------------- tiled GEMM: C[M,N] = A[M,K] * B[N,K]^T, scaled epilogue ----------------
__global__ __launch_bounds__(256) void gemm_kernel(const float* __restrict__ A,
                                                   const float* __restrict__ B,
                                                   float* __restrict__ C,
                                                   const float* __restrict__ rsc,
                                                   const float* __restrict__ wsum,
                                                   float inv_n, int N, int K) {
    __shared__ float As[16][68];
    __shared__ float Bs[16][68];
    int tid = threadIdx.x;
    int tx = tid & 15, ty = tid >> 4;
    int m0 = blockIdx.y << 6, n0 = blockIdx.x << 6;
    int lr = tid >> 4, lc = tid & 15;
    float acc[4][4] = {{0.f}};
    for (int k0 = 0; k0 < K; k0 += 16) {
        #pragma unroll
        for (int i = 0; i < 4; ++i) {
            As[lc][lr + 16 * i] = A[(size_t)(m0 + lr + 16 * i) * K + k0 + lc];
            Bs[lc][lr + 16 * i] = B[(size_t)(n0 + lr + 16 * i) * K + k0 + lc];
        }
        __syncthreads();
        #pragma unroll
        for (int kk = 0; kk < 16; ++kk) {
            float a0 = As[kk][ty * 4 + 0], a1 = As[kk][ty * 4 + 1];
            float a2 = As[kk][ty * 4 + 2], a3 = As[kk][ty * 4 + 3];
            float b0 = Bs[kk][tx * 4 + 0], b1 = Bs[kk][tx * 4 + 1];
            float b2 = Bs[kk][tx * 4 + 2], b3 = Bs[kk][tx * 4 + 3];
            acc[0][0] = fmaf(a0, b0, acc[0][0]); acc[0][1] = fmaf(a0, b1, acc[0][1]);
            acc[0][2] = fmaf(a0, b2, acc[0][2]); acc[0][3] = fmaf(a0, b3, acc[0][3]);
            acc[1][0] = fmaf(a1, b0, acc[1][0]); acc[1][1] = fmaf(a1, b1, acc[1][1]);
            acc[1][2] = fmaf(a1, b2, acc[1][2]); acc[1][3] = fmaf(a1, b3, acc[1][3]);
            acc[2][0] = fmaf(a2, b0, acc[2][0]); acc[2][1] = fmaf(a2, b1, acc[2][1]);
            acc[2][2] = fmaf(a2, b2, acc[2][2]); acc[2][3] = fmaf(a2, b3, acc[2][3]);
            acc[3][0] = fmaf(a3, b0, acc[3][0]); acc[3][1] = fmaf(a3, b1, acc[3][1]);
            acc[3][2] = fmaf(a3, b2, acc[3][2]); acc[3][3] = fmaf(a3, b3, acc[3][3]);
        }
        __syncthreads();
    }
    float wsc = fmaxf(wsum[0] * inv_n, 1e-5f);
    #pragma unroll
    for (int i = 0; i < 4; ++i) {
        int m = m0 + ty * 4 + i;
        float s = rsc[m] * wsc;
        #pragma unroll
        for (int j = 0; j < 4; ++j)
            C[(size_t)m * N + n0 + tx * 4 + j] = acc[i][j] * s;
    }
}

// ---------------- RoPE table: tab[s*64 + d] = cos, tab[s*64+32+d] = sin ----------------
__global__ __launch_bounds__(256) void rope_table_kernel(float* __restrict__ tab) {
    int i = blockIdx.x * 256 + threadIdx.x;     // S*32 threads
    int sp = i >> 5, d = i & 31;
    float inv = (float)pow(10000.0, -(double)d / 32.0);
    float ang = (float)sp * inv;
    tab[sp * 64 + d]      = cosf(ang);
    tab[sp * 64 + 32 + d] = sinf(ang);
}

// ---------------- RoPE apply (in-place on qkv; q heads 0..31, k heads 32..39) ----------------
__global__ __launch_bounds__(256) void rope_apply_kernel(float* __restrict__ qkv,
                                                         const float* __restrict__ tab) {
    int i = blockIdx.x * 256 + threadIdx.x;     // MTOK*40*32 threads
    int d = i & 31;
    int hh = (i >> 5) % 40;
    int row = i / 1280;
    int sp = row & (SS - 1);
    size_t base = (size_t)row * QKVO + (hh < 32 ? hh * 64 : HH + (hh - 32) * 64);
    float c = tab[sp * 64 + d], sn = tab[sp * 64 + 32 + d];
    float xr = qkv[base + d], xi = qkv[base + d + 32];
    qkv[base + d]      = xr * c - xi * sn;
    qkv[base + d + 32] = xr * sn + xi * c;
}

// ---------------- flash-style tiled attention (fp32 exact) ----------------
// grid (s-tile 32, h 32, b 2); block 256 = 16x16 threads, 4x4 elems each.
// Q,K staged transposed [d][row] stride 68 (b128 reads, 2-way banks free);
// P reuses K buffer; online softmax state replicated across 16-lane row group.
__global__ __launch_bounds__(256) void attn_tile_kernel(const float* __restrict__ qkv,
                                                        float* __restrict__ outp) {
    __shared__ float Qs[64][68];    // [d][r]
    __shared__ float KPs[64][68];   // K: [d][t]  then  P: [t][r]
    __shared__ float Vs[64][64];    // [t][d]
    int tid = threadIdx.x;
    int tx = tid & 15, ty = tid >> 4;          // 16x16
    int s0 = blockIdx.x << 6;
    int h  = blockIdx.y;
    int b  = blockIdx.z;
    int kh = h >> 2;                           // G = 4
    const float* Kbase = qkv + (size_t)b * SS * QKVO + HH + kh * HD_;
    const float* Vbase = Kbase + NKV_ * HD_;

    // stage Q (transposed, 1/8 folded in)
    {
        int r = tid >> 2;                      // 0..63
        int d0 = (tid & 3) << 4;               // 0,16,32,48
        const float* src = qkv + ((size_t)(b * SS + s0 + r)) * QKVO + h * HD_ + d0;
        #pragma unroll
        for (int k4 = 0; k4 < 4; ++k4) {
            float4 v = *(const float4*)(src + k4 * 4);
            Qs[d0 + k4 * 4 + 0][r] = v.x * 0.125f;
            Qs[d0 + k4 * 4 + 1][r] = v.y * 0.125f;
            Qs[d0 + k4 * 4 + 2][r] = v.z * 0.125f;
            Qs[d0 + k4 * 4 + 3][r] = v.w * 0.125f;
        }
    }

    float m[4]    = {-INFINITY, -INFINITY, -INFINITY, -INFINITY};
    float l[4]    = {0.f, 0.f, 0.f, 0.f};
    float o[4][4] = {{0.f}};

    for (int t0 = 0; t0 <= s0; t0 += 64) {
        __syncthreads();                        // protect KPs/Vs from prior iter readers
        // stage K (transposed) and V (natural)
        {
            int r = tid >> 2;
            int d0 = (tid & 3) << 4;
            const float* ksrc = Kbase + (size_t)(t0 + r) * QKVO + d0;
            const float* vsrc = Vbase + (size_t)(t0 + r) * QKVO + d0;
            #pragma unroll
            for (int k4 = 0; k4 < 4; ++k4) {
                float4 kv = *(const float4*)(ksrc + k4 * 4);
                KPs[d0 + k4 * 4 + 0][r] = kv.x;
                KPs[d0 + k4 * 4 + 1][r] = kv.y;
                KPs[d0 + k4 * 4 + 2][r] = kv.z;
                KPs[d0 + k4 * 4 + 3][r] = kv.w;
                *(float4*)&Vs[r][d0 + k4 * 4] = *(const float4*)(vsrc + k4 * 4);
            }
        }
        __syncthreads();

        // S = Q K^T  (64x64, k-dim = d)
        float sa[4][4] = {{0.f}};
        #pragma unroll 8
        for (int kk = 0; kk < 64; ++kk) {
            float4 qv = *(const float4*)&Qs[kk][ty << 2];
            float4 kv = *(const float4*)&KPs[kk][tx << 2];
            sa[0][0] = fmaf(qv.x, kv.x, sa[0][0]); sa[0][1] = fmaf(qv.x, kv.y, sa[0][1]);
            sa[0][2] = fmaf(qv.x, kv.z, sa[0][2]); sa[0][3] = fmaf(qv.x, kv.w, sa[0][3]);
            sa[1][0] = fmaf(qv.y, kv.x, sa[1][0]); sa[1][1] = fmaf(qv.y, kv.y, sa[1][1]);
            sa[1][2] = fmaf(qv.y, kv.z, sa[1][2]); sa[1][3] = fmaf(qv.y, kv.w, sa[1][3]);
            sa[2][0] = fmaf(qv.z, kv.x, sa[2][0]); sa[2][1] = fmaf(qv.z, kv.y, sa[2][1]);
            sa[2][2] = fmaf(qv.z, kv.z, sa[2][2]); sa[2][3] = fmaf(qv.z, kv.w, sa[2][3]);
            sa[3][0] = fmaf(qv.w, kv.x, sa[3][0]); sa[3][1] = fmaf(qv.w, kv.y, sa[3][1]);
            sa[3][2] = fmaf(qv.w, kv.z, sa[3][2]); sa[3][3] = fmaf(qv.w, kv.w, sa[3][3]);
        }

        // causal mask on the diagonal tile only (t0 == s0; earlier tiles are full)
        if (t0 == s0) {
            #pragma unroll
            for (int i = 0; i < 4; ++i)
                #pragma unroll
                for (int j = 0; j < 4; ++j)
                    if ((tx << 2) + j > (ty << 2) + i) sa[i][j] = -INFINITY;
        }

        // online softmax update (state replicated across the 16 lanes of a row group)
        #pragma unroll
        for (int i = 0; i < 4; ++i) {
            float rm = fmaxf(fmaxf(sa[i][0], sa[i][1]), fmaxf(sa[i][2], sa[i][3]));
            rm = fmaxf(rm, __shfl_xor(rm, 1, 64));
            rm = fmaxf(rm, __shfl_xor(rm, 2, 64));
            rm = fmaxf(rm, __shfl_xor(rm, 4, 64));
            rm = fmaxf(rm, __shfl_xor(rm, 8, 64));
            float mn = fmaxf(m[i], rm);
            float al = __expf(m[i] - mn);
            float p0 = __expf(sa[i][0] - mn);
            float p1 = __expf(sa[i][1] - mn);
            float p2 = __expf(sa[i][2] - mn);
            float p3 = __expf(sa[i][3] - mn);
            float rs = (p0 + p1) + (p2 + p3);
            rs += __shfl_xor(rs, 1, 64);
            rs += __shfl_xor(rs, 2, 64);
            rs += __shfl_xor(rs, 4, 64);
            rs += __shfl_xor(rs, 8, 64);
            l[i] = l[i] * al + rs;
            m[i] = mn;
            o[i][0] *= al; o[i][1] *= al; o[i][2] *= al; o[i][3] *= al;
            sa[i][0] = p0; sa[i][1] = p1; sa[i][2] = p2; sa[i][3] = p3;
        }

        __syncthreads();                        // everyone done reading K before P overwrite
        // write P transposed into KPs: P[t][r]
        #pragma unroll
        for (int j = 0; j < 4; ++j) {
            float4 w;
            w.x = sa[0][j]; w.y = sa[1][j]; w.z = sa[2][j]; w.w = sa[3][j];
            *(float4*)&KPs[(tx << 2) + j][ty << 2] = w;
        }
        __syncthreads();

        // O += P V  (k-dim = t)
        #pragma unroll 8
        for (int kk = 0; kk < 64; ++kk) {
            float4 pv = *(const float4*)&KPs[kk][ty << 2];
            float4 vv = *(const float4*)&Vs[kk][tx << 2];
            o[0][0] = fmaf(pv.x, vv.x, o[0][0]); o[0][1] = fmaf(pv.x, vv.y, o[0][1]);
            o[0][2] = fmaf(pv.x, vv.z, o[0][2]); o[0][3] = fmaf(pv.x, vv.w, o[0][3]);
            o[1][0] = fmaf(pv.y, vv.x, o[1][0]); o[1][1] = fmaf(pv.y, vv.y, o[1][1]);
            o[1][2] = fmaf(pv.y, vv.z, o[1][2]); o[1][3] = fmaf(pv.y, vv.w, o[1][3]);
            o[2][0] = fmaf(pv.z, vv.x, o[2][0]); o[2][1] = fmaf(pv.z, vv.y, o[2][1]);
            o[2][2] = fmaf(pv.z, vv.z, o[2][2]); o[2][3] = fmaf(pv.z, vv.w, o[2][3]);
            o[3][0] = fmaf(pv.w, vv.x, o[3][0]); o[3][1] = fmaf(pv.w, vv.y, o[3][1]);
            o[3][2] = fmaf(pv.w, vv.z, o[3][2]); o[3][3] = fmaf(pv.w, vv.w, o[3][3]);
        }
    }

    // epilogue: O / l, coalesced float4 stores
    #pragma unroll
    for (int i = 0; i < 4; ++i) {
        int row = s0 + (ty << 2) + i;
        float inv = 1.f / l[i];
        float4 res;
        res.x = o[i][0] * inv; res.y = o[i][1] * inv;
        res.z = o[i][2] * inv; res.w = o[i][3] * inv;
        *(float4*)&outp[((size_t)(b * SS + row)) * HH + h * HD_ + (tx << 2)] = res;
    }
}

extern "C" void kernel_launch(void* const* d_in, const int* in_sizes, int n_in,
                              void* d_out, int out_size, void* d_ws, size_t ws_size,
                              hipStream_t stream) {
    const float* x      = (const float*)d_in[0];
    const float* w_norm = (const float*)d_in[1];
    const float* w_qkv  = (const float*)d_in[2];
    const float* w_out  = (const float*)d_in[3];
    float* out = (float*)d_out;
    char* ws = (char*)d_ws;

    float* scal  = (float*)(ws + 0);          // [0]=sum|w_qkv|, [1]=sum|w_out|
    float* rope  = (float*)(ws + 64);         // 2048*64 floats
    float* xq    = (float*)(ws + 524352);     // 4096*2048 floats (quantized acts, reused)
    float* xsc   = (float*)(ws + 34078784);   // 4096 floats (row scales)
    float* wq1   = (float*)(ws + 34095168);   // 3072*2048 floats
    float* wq2   = (float*)(ws + 59260992);   // 2048*2048 floats
    float* qkv   = (float*)(ws + 76038208);   // 4096*3072 floats
    float* attno = (float*)(ws + 126369856);  // 4096*2048 floats

    hipMemsetAsync(scal, 0, 64, stream);
    absum_kernel<<<2048, 256, 0, stream>>>(w_qkv, scal + 0, QKVO * HH);
    absum_kernel<<<2048, 256, 0, stream>>>(w_out, scal + 1, HH * HH);
    wquant_kernel<<<8192, 256, 0, stream>>>(w_qkv, wq1, scal + 0, 1.0f / 6291456.0f, QKVO * HH);
    wquant_kernel<<<8192, 256, 0, stream>>>(w_out, wq2, scal + 1, 1.0f / 4194304.0f, HH * HH);
    rmsq_kernel<<<MTOK, 256, 0, stream>>>(x, w_norm, xq, xsc);
    gemm_kernel<<<dim3(QKVO / 64, MTOK / 64), 256, 0, stream>>>(xq, wq1, qkv, xsc, scal + 0,
                                                                1.0f / 6291456.0f, QKVO, HH);
    rope_table_kernel<<<SS * 32 / 256, 256, 0, stream>>>(rope);
    rope_apply_kernel<<<MTOK * 40 * 32 / 256, 256, 0, stream>>>(qkv, rope);
    attn_tile_kernel<<<dim3(SS / 64, NH_, 2), 256, 0, stream>>>(qkv, attno);
    rowq_kernel<<<MTOK, 256, 0, stream>>>(attno, xq, xsc);
    gemm_kernel<<<dim3(HH / 64, MTOK / 64), 256, 0, stream>>>(xq, wq2, out, xsc, scal + 1,
                                                              1.0f / 4194304.0f, HH, HH);
}

// Round 4
// 1486.106 us; speedup vs baseline: 4.2975x; 1.5643x over previous
//
#include <hip/hip_runtime.h>
#include <math.h>

#define SS   2048
#define HH   2048
#define NH_  32
#define NKV_ 8
#define HD_  64
#define QKVO 3072     // (32 + 2*8) * 64
#define MTOK 4096     // B * S

typedef short bf16x8 __attribute__((ext_vector_type(8)));   // 8 bf16 in 4 VGPRs
typedef float f32x4 __attribute__((ext_vector_type(4)));

__device__ inline ushort f2bf(float f) {                    // exact for our integer values
    return (ushort)(__float_as_uint(f) >> 16);
}

__device__ inline void gl_lds16(const void* g, void* l) {
    __builtin_amdgcn_global_load_lds((const __attribute__((address_space(1))) void*)g,
                                     (__attribute__((address_space(3))) void*)l, 16, 0, 0);
}

// ---------------- sum |w| reduction ----------------
__global__ __launch_bounds__(256) void absum_kernel(const float* __restrict__ w,
                                                    float* __restrict__ out, int n) {
    __shared__ float red[256];
    int tid = threadIdx.x;
    float acc = 0.f;
    for (int i = blockIdx.x * 256 + tid; i < n; i += gridDim.x * 256)
        acc += fabsf(w[i]);
    red[tid] = acc;
    __syncthreads();
    for (int s = 128; s > 0; s >>= 1) {
        if (tid < s) red[tid] += red[tid + s];
        __syncthreads();
    }
    if (tid == 0) atomicAdd(out, red[0]);
}

// ---------------- ternary weight quant -> bf16 ----------------
__global__ __launch_bounds__(256) void wquant_kernel(const float* __restrict__ w,
                                                     ushort* __restrict__ wq,
                                                     const float* __restrict__ sum,
                                                     float inv_n, int n) {
    float mean = fmaxf(sum[0] * inv_n, 1e-5f);
    float wsc = 1.f / mean;
    for (int i = blockIdx.x * 256 + threadIdx.x; i < n; i += gridDim.x * 256) {
        float q = rintf(w[i] * wsc);
        wq[i] = f2bf(fminf(fmaxf(q, -1.f), 1.f));
    }
}

// ---------------- RMSNorm + activation quant -> bf16 (one block per row, H=2048) ----------------
__global__ __launch_bounds__(256) void rmsq_kernel(const float* __restrict__ x,
                                                   const float* __restrict__ wn,
                                                   ushort* __restrict__ xq,
                                                   float* __restrict__ xsc) {
    __shared__ float red[256];
    int tid = threadIdx.x;
    const float* xr = x + (size_t)blockIdx.x * HH;
    float4 a = ((const float4*)xr)[tid];
    float4 b = ((const float4*)xr)[tid + 256];
    float s2 = a.x*a.x + a.y*a.y + a.z*a.z + a.w*a.w
             + b.x*b.x + b.y*b.y + b.z*b.z + b.w*b.w;
    red[tid] = s2;
    __syncthreads();
    for (int s = 128; s > 0; s >>= 1) { if (tid < s) red[tid] += red[tid + s]; __syncthreads(); }
    float r = rsqrtf(red[0] * (1.f / HH) + 1e-5f);
    __syncthreads();
    float4 wa = ((const float4*)wn)[tid];
    float4 wb = ((const float4*)wn)[tid + 256];
    float4 na, nb;
    na.x = a.x * r * wa.x; na.y = a.y * r * wa.y; na.z = a.z * r * wa.z; na.w = a.w * r * wa.w;
    nb.x = b.x * r * wb.x; nb.y = b.y * r * wb.y; nb.z = b.z * r * wb.z; nb.w = b.w * r * wb.w;
    float am = fabsf(na.x);
    am = fmaxf(am, fabsf(na.y)); am = fmaxf(am, fabsf(na.z)); am = fmaxf(am, fabsf(na.w));
    am = fmaxf(am, fabsf(nb.x)); am = fmaxf(am, fabsf(nb.y));
    am = fmaxf(am, fabsf(nb.z)); am = fmaxf(am, fabsf(nb.w));
    red[tid] = am;
    __syncthreads();
    for (int s = 128; s > 0; s >>= 1) { if (tid < s) red[tid] = fmaxf(red[tid], red[tid + s]); __syncthreads(); }
    float amax = fmaxf(red[0], 1e-5f);
    float xs = 127.f / amax;
    if (tid == 0) xsc[blockIdx.x] = amax * (1.f / 127.f);
    ushort* qr = xq + (size_t)blockIdx.x * HH;
    ushort4 ua, ub;
    ua.x = f2bf(fminf(fmaxf(rintf(na.x * xs), -128.f), 127.f));
    ua.y = f2bf(fminf(fmaxf(rintf(na.y * xs), -128.f), 127.f));
    ua.z = f2bf(fminf(fmaxf(rintf(na.z * xs), -128.f), 127.f));
    ua.w = f2bf(fminf(fmaxf(rintf(na.w * xs), -128.f), 127.f));
    ub.x = f2bf(fminf(fmaxf(rintf(nb.x * xs), -128.f), 127.f));
    ub.y = f2bf(fminf(fmaxf(rintf(nb.y * xs), -128.f), 127.f));
    ub.z = f2bf(fminf(fmaxf(rintf(nb.z * xs), -128.f), 127.f));
    ub.w = f2bf(fminf(fmaxf(rintf(nb.w * xs), -128.f), 127.f));
    ((ushort4*)qr)[tid] = ua;
    ((ushort4*)qr)[tid + 256] = ub;
}

// ---------------- row absmax quant -> bf16 (attention output, H=2048) ----------------
__global__ __launch_bounds__(256) void rowq_kernel(const float* __restrict__ x,
                                                   ushort* __restrict__ xq,
                                                   float* __restrict__ xsc) {
    __shared__ float red[256];
    int tid = threadIdx.x;
    const float* xr = x + (size_t)blockIdx.x * HH;
    float4 a = ((const float4*)xr)[tid];
    float4 b = ((const float4*)xr)[tid + 256];
    float am = fabsf(a.x);
    am = fmaxf(am, fabsf(a.y)); am = fmaxf(am, fabsf(a.z)); am = fmaxf(am, fabsf(a.w));
    am = fmaxf(am, fabsf(b.x)); am = fmaxf(am, fabsf(b.y));
    am = fmaxf(am, fabsf(b.z)); am = fmaxf(am, fabsf(b.w));
    red[tid] = am;
    __syncthreads();
    for (int s = 128; s > 0; s >>= 1) { if (tid < s) red[tid] = fmaxf(red[tid], red[tid + s]); __syncthreads(); }
    float amax = fmaxf(red[0], 1e-5f);
    float xs = 127.f / amax;
    if (tid == 0) xsc[blockIdx.x] = amax * (1.f / 127.f);
    ushort* qr = xq + (size_t)blockIdx.x * HH;
    ushort4 ua, ub;
    ua.x = f2bf(fminf(fmaxf(rintf(a.x * xs), -128.f), 127.f));
    ua.y = f2bf(fminf(fmaxf(rintf(a.y * xs), -128.f), 127.f));
    ua.z = f2bf(fminf(fmaxf(rintf(a.z * xs), -128.f), 127.f));
    ua.w = f2bf(fminf(fmaxf(rintf(a.w * xs), -128.f), 127.f));
    ub.x = f2bf(fminf(fmaxf(rintf(b.x * xs), -128.f), 127.f));
    ub.y = f2bf(fminf(fmaxf(rintf(b.y * xs), -128.f), 127.f));
    ub.z = f2bf(fminf(fmaxf(rintf(b.z * xs), -128.f), 127.f));
    ub.w = f2bf(fminf(fmaxf(rintf(b.w * xs), -128.f), 127.f));
    ((ushort4*)qr)[tid] = ua;
    ((ushort4*)qr)[tid + 256] = ub;
}

// ---------------- bf16 MFMA GEMM (m97 structure): C[M,N] = A[M,K]*B[N,K]^T, scaled ----------------
// 128x128 tile, BK=32, global_load_lds width 16, 4 waves 2x2, 4x4 16x16x32 MFMA per wave.
// Bit-exact: A in [-128,127], B in {-1,0,1}, fp32 accumulate.
__global__ __launch_bounds__(256) void gemm_mfma_kernel(const ushort* __restrict__ A,
                                                        const ushort* __restrict__ B,
                                                        float* __restrict__ C,
                                                        const float* __restrict__ rsc,
                                                        const float* __restrict__ wsum,
                                                        float inv_n, int N, int K) {
    __shared__ __align__(16) ushort Alds[128 * 32];
    __shared__ __align__(16) ushort Blds[128 * 32];
    int tid = threadIdx.x;
    int lane = tid & 63, w = tid >> 6;
    int quad = lane >> 4, l15 = lane & 15;
    int m0 = blockIdx.y << 7, n0 = blockIdx.x << 7;
    int wm = (w >> 1) << 6, wn = (w & 1) << 6;
    // staging: wave w covers LDS bytes [w*2048, w*2048+2048) via 2 instrs of 1024 B
    int srow = (w << 5) + (lane >> 2);          // + 16 for second instr
    int scol = (lane & 3) << 3;                 // k-element offset 0,8,16,24
    const ushort* Arow = A + (size_t)(m0 + srow) * K + scol;
    const ushort* Brow = B + (size_t)(n0 + srow) * K + scol;
    ushort* Adst = &Alds[w << 10];              // wave-uniform LDS base (HW adds lane*16)
    ushort* Bdst = &Blds[w << 10];

    f32x4 acc[4][4] = {};
    for (int k0 = 0; k0 < K; k0 += 32) {
        gl_lds16(Arow + k0, Adst);
        gl_lds16(Arow + (size_t)16 * K + k0, Adst + 512);
        gl_lds16(Brow + k0, Bdst);
        gl_lds16(Brow + (size_t)16 * K + k0, Bdst + 512);
        __syncthreads();
        bf16x8 af[4], bfr[4];
        #pragma unroll
        for (int i = 0; i < 4; ++i) {
            af[i]  = *(const bf16x8*)&Alds[(wm + i * 16 + l15) * 32 + quad * 8];
            bfr[i] = *(const bf16x8*)&Blds[(wn + i * 16 + l15) * 32 + quad * 8];
        }
        #pragma unroll
        for (int i = 0; i < 4; ++i)
            #pragma unroll
            for (int j = 0; j < 4; ++j)
                acc[i][j] = __builtin_amdgcn_mfma_f32_16x16x32_bf16(af[i], bfr[j], acc[i][j], 0, 0, 0);
        __syncthreads();
    }

    float wsc = fmaxf(wsum[0] * inv_n, 1e-5f);
    #pragma unroll
    for (int i = 0; i < 4; ++i) {
        #pragma unroll
        for (int r = 0; r < 4; ++r) {
            int row = m0 + wm + i * 16 + quad * 4 + r;
            float s = rsc[row] * wsc;
            #pragma unroll
            for (int j = 0; j < 4; ++j) {
                int col = n0 + wn + j * 16 + l15;
                C[(size_t)row * N + col] = acc[i][j][r] * s;
            }
        }
    }
}

// ---------------- RoPE table: tab[s*64 + d] = cos, tab[s*64+32+d] = sin ----------------
__global__ __launch_bounds__(256) void rope_table_kernel(float* __restrict__ tab) {
    int i = blockIdx.x * 256 + threadIdx.x;     // S*32 threads
    int sp = i >> 5, d = i & 31;
    float inv = (float)pow(10000.0, -(double)d / 32.0);
    float ang = (float)sp * inv;
    tab[sp * 64 + d]      = cosf(ang);
    tab[sp * 64 + 32 + d] = sinf(ang);
}

// ---------------- RoPE apply (in-place on qkv; q heads 0..31, k heads 32..39) ----------------
__global__ __launch_bounds__(256) void rope_apply_kernel(float* __restrict__ qkv,
                                                         const float* __restrict__ tab) {
    int i = blockIdx.x * 256 + threadIdx.x;     // MTOK*40*32 threads
    int d = i & 31;
    int hh = (i >> 5) % 40;
    int row = i / 1280;
    int sp = row & (SS - 1);
    size_t base = (size_t)row * QKVO + (hh < 32 ? hh * 64 : HH + (hh - 32) * 64);
    float c = tab[sp * 64 + d], sn = tab[sp * 64 + 32 + d];
    float xr = qkv[base + d], xi = qkv[base + d + 32];
    qkv[base + d]      = xr * c - xi * sn;
    qkv[base + d + 32] = xr * sn + xi * c;
}

// ---------------- flash-style tiled attention (fp32 exact) ----------------
__global__ __launch_bounds__(256) void attn_tile_kernel(const float* __restrict__ qkv,
                                                        float* __restrict__ outp) {
    __shared__ float Qs[64][68];    // [d][r]
    __shared__ float KPs[64][68];   // K: [d][t]  then  P: [t][r]
    __shared__ float Vs[64][64];    // [t][d]
    int tid = threadIdx.x;
    int tx = tid & 15, ty = tid >> 4;          // 16x16
    int s0 = blockIdx.x << 6;
    int h  = blockIdx.y;
    int b  = blockIdx.z;
    int kh = h >> 2;                           // G = 4
    const float* Kbase = qkv + (size_t)b * SS * QKVO + HH + kh * HD_;
    const float* Vbase = Kbase + NKV_ * HD_;

    {
        int r = tid >> 2;
        int d0 = (tid & 3) << 4;
        const float* src = qkv + ((size_t)(b * SS + s0 + r)) * QKVO + h * HD_ + d0;
        #pragma unroll
        for (int k4 = 0; k4 < 4; ++k4) {
            float4 v = *(const float4*)(src + k4 * 4);
            Qs[d0 + k4 * 4 + 0][r] = v.x * 0.125f;
            Qs[d0 + k4 * 4 + 1][r] = v.y * 0.125f;
            Qs[d0 + k4 * 4 + 2][r] = v.z * 0.125f;
            Qs[d0 + k4 * 4 + 3][r] = v.w * 0.125f;
        }
    }

    float m[4]    = {-INFINITY, -INFINITY, -INFINITY, -INFINITY};
    float l[4]    = {0.f, 0.f, 0.f, 0.f};
    float o[4][4] = {{0.f}};

    for (int t0 = 0; t0 <= s0; t0 += 64) {
        __syncthreads();
        {
            int r = tid >> 2;
            int d0 = (tid & 3) << 4;
            const float* ksrc = Kbase + (size_t)(t0 + r) * QKVO + d0;
            const float* vsrc = Vbase + (size_t)(t0 + r) * QKVO + d0;
            #pragma unroll
            for (int k4 = 0; k4 < 4; ++k4) {
                float4 kv = *(const float4*)(ksrc + k4 * 4);
                KPs[d0 + k4 * 4 + 0][r] = kv.x;
                KPs[d0 + k4 * 4 + 1][r] = kv.y;
                KPs[d0 + k4 * 4 + 2][r] = kv.z;
                KPs[d0 + k4 * 4 + 3][r] = kv.w;
                *(float4*)&Vs[r][d0 + k4 * 4] = *(const float4*)(vsrc + k4 * 4);
            }
        }
        __syncthreads();

        float sa[4][4] = {{0.f}};
        #pragma unroll 8
        for (int kk = 0; kk < 64; ++kk) {
            float4 qv = *(const float4*)&Qs[kk][ty << 2];
            float4 kv = *(const float4*)&KPs[kk][tx << 2];
            sa[0][0] = fmaf(qv.x, kv.x, sa[0][0]); sa[0][1] = fmaf(qv.x, kv.y, sa[0][1]);
            sa[0][2] = fmaf(qv.x, kv.z, sa[0][2]); sa[0][3] = fmaf(qv.x, kv.w, sa[0][3]);
            sa[1][0] = fmaf(qv.y, kv.x, sa[1][0]); sa[1][1] = fmaf(qv.y, kv.y, sa[1][1]);
            sa[1][2] = fmaf(qv.y, kv.z, sa[1][2]); sa[1][3] = fmaf(qv.y, kv.w, sa[1][3]);
            sa[2][0] = fmaf(qv.z, kv.x, sa[2][0]); sa[2][1] = fmaf(qv.z, kv.y, sa[2][1]);
            sa[2][2] = fmaf(qv.z, kv.z, sa[2][2]); sa[2][3] = fmaf(qv.z, kv.w, sa[2][3]);
            sa[3][0] = fmaf(qv.w, kv.x, sa[3][0]); sa[3][1] = fmaf(qv.w, kv.y, sa[3][1]);
            sa[3][2] = fmaf(qv.w, kv.z, sa[3][2]); sa[3][3] = fmaf(qv.w, kv.w, sa[3][3]);
        }

        if (t0 == s0) {
            #pragma unroll
            for (int i = 0; i < 4; ++i)
                #pragma unroll
                for (int j = 0; j < 4; ++j)
                    if ((tx << 2) + j > (ty << 2) + i) sa[i][j] = -INFINITY;
        }

        #pragma unroll
        for (int i = 0; i < 4; ++i) {
            float rm = fmaxf(fmaxf(sa[i][0], sa[i][1]), fmaxf(sa[i][2], sa[i][3]));
            rm = fmaxf(rm, __shfl_xor(rm, 1, 64));
            rm = fmaxf(rm, __shfl_xor(rm, 2, 64));
            rm = fmaxf(rm, __shfl_xor(rm, 4, 64));
            rm = fmaxf(rm, __shfl_xor(rm, 8, 64));
            float mn = fmaxf(m[i], rm);
            float al = __expf(m[i] - mn);
            float p0 = __expf(sa[i][0] - mn);
            float p1 = __expf(sa[i][1] - mn);
            float p2 = __expf(sa[i][2] - mn);
            float p3 = __expf(sa[i][3] - mn);
            float rs = (p0 + p1) + (p2 + p3);
            rs += __shfl_xor(rs, 1, 64);
            rs += __shfl_xor(rs, 2, 64);
            rs += __shfl_xor(rs, 4, 64);
            rs += __shfl_xor(rs, 8, 64);
            l[i] = l[i] * al + rs;
            m[i] = mn;
            o[i][0] *= al; o[i][1] *= al; o[i][2] *= al; o[i][3] *= al;
            sa[i][0] = p0; sa[i][1] = p1; sa[i][2] = p2; sa[i][3] = p3;
        }

        __syncthreads();
        #pragma unroll
        for (int j = 0; j < 4; ++j) {
            float4 w;
            w.x = sa[0][j]; w.y = sa[1][j]; w.z = sa[2][j]; w.w = sa[3][j];
            *(float4*)&KPs[(tx << 2) + j][ty << 2] = w;
        }
        __syncthreads();

        #pragma unroll 8
        for (int kk = 0; kk < 64; ++kk) {
            float4 pv = *(const float4*)&KPs[kk][ty << 2];
            float4 vv = *(const float4*)&Vs[kk][tx << 2];
            o[0][0] = fmaf(pv.x, vv.x, o[0][0]); o[0][1] = fmaf(pv.x, vv.y, o[0][1]);
            o[0][2] = fmaf(pv.x, vv.z, o[0][2]); o[0][3] = fmaf(pv.x, vv.w, o[0][3]);
            o[1][0] = fmaf(pv.y, vv.x, o[1][0]); o[1][1] = fmaf(pv.y, vv.y, o[1][1]);
            o[1][2] = fmaf(pv.y, vv.z, o[1][2]); o[1][3] = fmaf(pv.y, vv.w, o[1][3]);
            o[2][0] = fmaf(pv.z, vv.x, o[2][0]); o[2][1] = fmaf(pv.z, vv.y, o[2][1]);
            o[2][2] = fmaf(pv.z, vv.z, o[2][2]); o[2][3] = fmaf(pv.z, vv.w, o[2][3]);
            o[3][0] = fmaf(pv.w, vv.x, o[3][0]); o[3][1] = fmaf(pv.w, vv.y, o[3][1]);
            o[3][2] = fmaf(pv.w, vv.z, o[3][2]); o[3][3] = fmaf(pv.w, vv.w, o[3][3]);
        }
    }

    #pragma unroll
    for (int i = 0; i < 4; ++i) {
        int row = s0 + (ty << 2) + i;
        float inv = 1.f / l[i];
        float4 res;
        res.x = o[i][0] * inv; res.y = o[i][1] * inv;
        res.z = o[i][2] * inv; res.w = o[i][3] * inv;
        *(float4*)&outp[((size_t)(b * SS + row)) * HH + h * HD_ + (tx << 2)] = res;
    }
}

extern "C" void kernel_launch(void* const* d_in, const int* in_sizes, int n_in,
                              void* d_out, int out_size, void* d_ws, size_t ws_size,
                              hipStream_t stream) {
    const float* x      = (const float*)d_in[0];
    const float* w_norm = (const float*)d_in[1];
    const float* w_qkv  = (const float*)d_in[2];
    const float* w_out  = (const float*)d_in[3];
    float* out = (float*)d_out;
    char* ws = (char*)d_ws;

    float*  scal  = (float*)(ws + 0);          // [0]=sum|w_qkv|, [1]=sum|w_out|
    float*  rope  = (float*)(ws + 64);         // 2048*64 f32
    ushort* xq    = (ushort*)(ws + 524352);    // 4096*2048 bf16
    float*  xsc   = (float*)(ws + 17301568);   // 4096 f32
    ushort* wq1   = (ushort*)(ws + 17317952);  // 3072*2048 bf16
    ushort* wq2   = (ushort*)(ws + 29900864);  // 2048*2048 bf16
    float*  qkv   = (float*)(ws + 38289472);   // 4096*3072 f32
    float*  attno = (float*)(ws + 88621120);   // 4096*2048 f32

    hipMemsetAsync(scal, 0, 64, stream);
    absum_kernel<<<2048, 256, 0, stream>>>(w_qkv, scal + 0, QKVO * HH);
    absum_kernel<<<2048, 256, 0, stream>>>(w_out, scal + 1, HH * HH);
    wquant_kernel<<<8192, 256, 0, stream>>>(w_qkv, wq1, scal + 0, 1.0f / 6291456.0f, QKVO * HH);
    wquant_kernel<<<8192, 256, 0, stream>>>(w_out, wq2, scal + 1, 1.0f / 4194304.0f, HH * HH);
    rmsq_kernel<<<MTOK, 256, 0, stream>>>(x, w_norm, xq, xsc);
    gemm_mfma_kernel<<<dim3(QKVO / 128, MTOK / 128), 256, 0, stream>>>(xq, wq1, qkv, xsc, scal + 0,
                                                                       1.0f / 6291456.0f, QKVO, HH);
    rope_table_kernel<<<SS * 32 / 256, 256, 0, stream>>>(rope);
    rope_apply_kernel<<<MTOK * 40 * 32 / 256, 256, 0, stream>>>(qkv, rope);
    attn_tile_kernel<<<dim3(SS / 64, NH_, 2), 256, 0, stream>>>(qkv, attno);
    rowq_kernel<<<MTOK, 256, 0, stream>>>(attno, xq, xsc);
    gemm_mfma_kernel<<<dim3(HH / 128, MTOK / 128), 256, 0, stream>>>(xq, wq2, out, xsc, scal + 1,
                                                                     1.0f / 4194304.0f, HH, HH);
}

// Round 5
// 559.047 us; speedup vs baseline: 11.4241x; 2.6583x over previous
//
#include <hip/hip_runtime.h>
#include <math.h>

#define SS   2048
#define HH   2048
#define NH_  32
#define NKV_ 8
#define HD_  64
#define QKVO 3072     // (32 + 2*8) * 64
#define MTOK 4096     // B * S

typedef short bf16x8 __attribute__((ext_vector_type(8)));     // 8 bf16 in 4 VGPRs
typedef _Float16 f16x8 __attribute__((ext_vector_type(8)));   // 8 fp16 in 4 VGPRs
typedef float f32x4 __attribute__((ext_vector_type(4)));

__device__ inline ushort f2bf(float f) {                      // exact for our integer values
    return (ushort)(__float_as_uint(f) >> 16);
}
__device__ inline ushort f2h(float f) {
    _Float16 h = (_Float16)f;
    return *(ushort*)&h;
}

__device__ inline void gl_lds16(const void* g, void* l) {
    __builtin_amdgcn_global_load_lds((const __attribute__((address_space(1))) void*)g,
                                     (__attribute__((address_space(3))) void*)l, 16, 0, 0);
}

// ---------------- sum |w| reduction ----------------
__global__ __launch_bounds__(256) void absum_kernel(const float* __restrict__ w,
                                                    float* __restrict__ out, int n) {
    __shared__ float red[256];
    int tid = threadIdx.x;
    float acc = 0.f;
    for (int i = blockIdx.x * 256 + tid; i < n; i += gridDim.x * 256)
        acc += fabsf(w[i]);
    red[tid] = acc;
    __syncthreads();
    for (int s = 128; s > 0; s >>= 1) {
        if (tid < s) red[tid] += red[tid + s];
        __syncthreads();
    }
    if (tid == 0) atomicAdd(out, red[0]);
}

// ---------------- ternary weight quant -> bf16 ----------------
__global__ __launch_bounds__(256) void wquant_kernel(const float* __restrict__ w,
                                                     ushort* __restrict__ wq,
                                                     const float* __restrict__ sum,
                                                     float inv_n, int n) {
    float mean = fmaxf(sum[0] * inv_n, 1e-5f);
    float wsc = 1.f / mean;
    for (int i = blockIdx.x * 256 + threadIdx.x; i < n; i += gridDim.x * 256) {
        float q = rintf(w[i] * wsc);
        wq[i] = f2bf(fminf(fmaxf(q, -1.f), 1.f));
    }
}

// ---------------- RMSNorm + activation quant -> bf16 (one block per row, H=2048) ----------------
__global__ __launch_bounds__(256) void rmsq_kernel(const float* __restrict__ x,
                                                   const float* __restrict__ wn,
                                                   ushort* __restrict__ xq,
                                                   float* __restrict__ xsc) {
    __shared__ float red[256];
    int tid = threadIdx.x;
    const float* xr = x + (size_t)blockIdx.x * HH;
    float4 a = ((const float4*)xr)[tid];
    float4 b = ((const float4*)xr)[tid + 256];
    float s2 = a.x*a.x + a.y*a.y + a.z*a.z + a.w*a.w
             + b.x*b.x + b.y*b.y + b.z*b.z + b.w*b.w;
    red[tid] = s2;
    __syncthreads();
    for (int s = 128; s > 0; s >>= 1) { if (tid < s) red[tid] += red[tid + s]; __syncthreads(); }
    float r = rsqrtf(red[0] * (1.f / HH) + 1e-5f);
    __syncthreads();
    float4 wa = ((const float4*)wn)[tid];
    float4 wb = ((const float4*)wn)[tid + 256];
    float4 na, nb;
    na.x = a.x * r * wa.x; na.y = a.y * r * wa.y; na.z = a.z * r * wa.z; na.w = a.w * r * wa.w;
    nb.x = b.x * r * wb.x; nb.y = b.y * r * wb.y; nb.z = b.z * r * wb.z; nb.w = b.w * r * wb.w;
    float am = fabsf(na.x);
    am = fmaxf(am, fabsf(na.y)); am = fmaxf(am, fabsf(na.z)); am = fmaxf(am, fabsf(na.w));
    am = fmaxf(am, fabsf(nb.x)); am = fmaxf(am, fabsf(nb.y));
    am = fmaxf(am, fabsf(nb.z)); am = fmaxf(am, fabsf(nb.w));
    red[tid] = am;
    __syncthreads();
    for (int s = 128; s > 0; s >>= 1) { if (tid < s) red[tid] = fmaxf(red[tid], red[tid + s]); __syncthreads(); }
    float amax = fmaxf(red[0], 1e-5f);
    float xs = 127.f / amax;
    if (tid == 0) xsc[blockIdx.x] = amax * (1.f / 127.f);
    ushort* qr = xq + (size_t)blockIdx.x * HH;
    ushort4 ua, ub;
    ua.x = f2bf(fminf(fmaxf(rintf(na.x * xs), -128.f), 127.f));
    ua.y = f2bf(fminf(fmaxf(rintf(na.y * xs), -128.f), 127.f));
    ua.z = f2bf(fminf(fmaxf(rintf(na.z * xs), -128.f), 127.f));
    ua.w = f2bf(fminf(fmaxf(rintf(na.w * xs), -128.f), 127.f));
    ub.x = f2bf(fminf(fmaxf(rintf(nb.x * xs), -128.f), 127.f));
    ub.y = f2bf(fminf(fmaxf(rintf(nb.y * xs), -128.f), 127.f));
    ub.z = f2bf(fminf(fmaxf(rintf(nb.z * xs), -128.f), 127.f));
    ub.w = f2bf(fminf(fmaxf(rintf(nb.w * xs), -128.f), 127.f));
    ((ushort4*)qr)[tid] = ua;
    ((ushort4*)qr)[tid + 256] = ub;
}

// ---------------- row absmax quant -> bf16 (attention output, H=2048) ----------------
__global__ __launch_bounds__(256) void rowq_kernel(const float* __restrict__ x,
                                                   ushort* __restrict__ xq,
                                                   float* __restrict__ xsc) {
    __shared__ float red[256];
    int tid = threadIdx.x;
    const float* xr = x + (size_t)blockIdx.x * HH;
    float4 a = ((const float4*)xr)[tid];
    float4 b = ((const float4*)xr)[tid + 256];
    float am = fabsf(a.x);
    am = fmaxf(am, fabsf(a.y)); am = fmaxf(am, fabsf(a.z)); am = fmaxf(am, fabsf(a.w));
    am = fmaxf(am, fabsf(b.x)); am = fmaxf(am, fabsf(b.y));
    am = fmaxf(am, fabsf(b.z)); am = fmaxf(am, fabsf(b.w));
    red[tid] = am;
    __syncthreads();
    for (int s = 128; s > 0; s >>= 1) { if (tid < s) red[tid] = fmaxf(red[tid], red[tid + s]); __syncthreads(); }
    float amax = fmaxf(red[0], 1e-5f);
    float xs = 127.f / amax;
    if (tid == 0) xsc[blockIdx.x] = amax * (1.f / 127.f);
    ushort* qr = xq + (size_t)blockIdx.x * HH;
    ushort4 ua, ub;
    ua.x = f2bf(fminf(fmaxf(rintf(a.x * xs), -128.f), 127.f));
    ua.y = f2bf(fminf(fmaxf(rintf(a.y * xs), -128.f), 127.f));
    ua.z = f2bf(fminf(fmaxf(rintf(a.z * xs), -128.f), 127.f));
    ua.w = f2bf(fminf(fmaxf(rintf(a.w * xs), -128.f), 127.f));
    ub.x = f2bf(fminf(fmaxf(rintf(b.x * xs), -128.f), 127.f));
    ub.y = f2bf(fminf(fmaxf(rintf(b.y * xs), -128.f), 127.f));
    ub.z = f2bf(fminf(fmaxf(rintf(b.z * xs), -128.f), 127.f));
    ub.w = f2bf(fminf(fmaxf(rintf(b.w * xs), -128.f), 127.f));
    ((ushort4*)qr)[tid] = ua;
    ((ushort4*)qr)[tid + 256] = ub;
}

// ---------------- bf16 MFMA GEMM (m97 structure): C[M,N] = A[M,K]*B[N,K]^T, scaled ----------------
__global__ __launch_bounds__(256) void gemm_mfma_kernel(const ushort* __restrict__ A,
                                                        const ushort* __restrict__ B,
                                                        float* __restrict__ C,
                                                        const float* __restrict__ rsc,
                                                        const float* __restrict__ wsum,
                                                        float inv_n, int N, int K) {
    __shared__ __align__(16) ushort Alds[128 * 32];
    __shared__ __align__(16) ushort Blds[128 * 32];
    int tid = threadIdx.x;
    int lane = tid & 63, w = tid >> 6;
    int quad = lane >> 4, l15 = lane & 15;
    int m0 = blockIdx.y << 7, n0 = blockIdx.x << 7;
    int wm = (w >> 1) << 6, wn = (w & 1) << 6;
    int srow = (w << 5) + (lane >> 2);
    int scol = (lane & 3) << 3;
    const ushort* Arow = A + (size_t)(m0 + srow) * K + scol;
    const ushort* Brow = B + (size_t)(n0 + srow) * K + scol;
    ushort* Adst = &Alds[w << 10];
    ushort* Bdst = &Blds[w << 10];

    f32x4 acc[4][4] = {};
    for (int k0 = 0; k0 < K; k0 += 32) {
        gl_lds16(Arow + k0, Adst);
        gl_lds16(Arow + (size_t)16 * K + k0, Adst + 512);
        gl_lds16(Brow + k0, Bdst);
        gl_lds16(Brow + (size_t)16 * K + k0, Bdst + 512);
        __syncthreads();
        bf16x8 af[4], bfr[4];
        #pragma unroll
        for (int i = 0; i < 4; ++i) {
            af[i]  = *(const bf16x8*)&Alds[(wm + i * 16 + l15) * 32 + quad * 8];
            bfr[i] = *(const bf16x8*)&Blds[(wn + i * 16 + l15) * 32 + quad * 8];
        }
        #pragma unroll
        for (int i = 0; i < 4; ++i)
            #pragma unroll
            for (int j = 0; j < 4; ++j)
                acc[i][j] = __builtin_amdgcn_mfma_f32_16x16x32_bf16(af[i], bfr[j], acc[i][j], 0, 0, 0);
        __syncthreads();
    }

    float wsc = fmaxf(wsum[0] * inv_n, 1e-5f);
    #pragma unroll
    for (int i = 0; i < 4; ++i) {
        #pragma unroll
        for (int r = 0; r < 4; ++r) {
            int row = m0 + wm + i * 16 + quad * 4 + r;
            float s = rsc[row] * wsc;
            #pragma unroll
            for (int j = 0; j < 4; ++j) {
                int col = n0 + wn + j * 16 + l15;
                C[(size_t)row * N + col] = acc[i][j][r] * s;
            }
        }
    }
}

// ---------------- RoPE table ----------------
__global__ __launch_bounds__(256) void rope_table_kernel(float* __restrict__ tab) {
    int i = blockIdx.x * 256 + threadIdx.x;     // S*32 threads
    int sp = i >> 5, d = i & 31;
    float inv = (float)pow(10000.0, -(double)d / 32.0);
    float ang = (float)sp * inv;
    tab[sp * 64 + d]      = cosf(ang);
    tab[sp * 64 + 32 + d] = sinf(ang);
}

// ---------------- RoPE apply -> fp16 q (x0.125) and k side buffers ----------------
__global__ __launch_bounds__(256) void rope_f16_kernel(const float* __restrict__ qkv,
                                                       const float* __restrict__ tab,
                                                       ushort* __restrict__ qh,
                                                       ushort* __restrict__ kh) {
    int i = blockIdx.x * 256 + threadIdx.x;     // MTOK*40*32 threads
    int d = i & 31;
    int hh = (i >> 5) % 40;
    int row = i / 1280;
    int sp = row & (SS - 1);
    size_t base = (size_t)row * QKVO + (hh < 32 ? hh * 64 : HH + (hh - 32) * 64);
    float c = tab[sp * 64 + d], sn = tab[sp * 64 + 32 + d];
    float xr = qkv[base + d], xi = qkv[base + d + 32];
    float ro = xr * c - xi * sn;
    float io = xr * sn + xi * c;
    if (hh < 32) {
        ushort* dst = qh + (size_t)row * HH + hh * 64;
        dst[d]      = f2h(ro * 0.125f);
        dst[d + 32] = f2h(io * 0.125f);
    } else {
        ushort* dst = kh + (size_t)row * (NKV_ * 64) + (hh - 32) * 64;
        dst[d]      = f2h(ro);
        dst[d + 32] = f2h(io);
    }
}

// ---------------- V -> fp16 transposed [b][kv][d][s] ----------------
__global__ __launch_bounds__(256) void vconv_kernel(const float* __restrict__ qkv,
                                                    ushort* __restrict__ vT) {
    int i = blockIdx.x * 256 + threadIdx.x;     // 2*8*64*2048 threads
    int t  = i & (SS - 1);
    int d  = (i >> 11) & 63;
    int kv = (i >> 17) & 7;
    int b  = i >> 20;
    vT[i] = f2h(qkv[((size_t)(b * SS + t)) * QKVO + HH + NKV_ * 64 + kv * 64 + d]);
}

// ---------------- MFMA flash attention (fp16 in, fp32 softmax/accum) ----------------
// grid (32 s-tiles, 32 heads, 2 b); 4 waves, wave w owns q-rows s0+w*16..+15.
// LDS rows padded to 72 halves (frag reads 2-way bank, free).
__global__ __launch_bounds__(256) void attn_mfma_kernel(const ushort* __restrict__ qh,
                                                        const ushort* __restrict__ kh,
                                                        const ushort* __restrict__ vT,
                                                        float* __restrict__ attno) {
    __shared__ ushort Qs[64 * 72];     // [qrow][d]
    __shared__ ushort Ks[64 * 72];     // [t][d]
    __shared__ ushort Vs[64 * 72];     // [d][t]
    __shared__ ushort Ps[4][16 * 72];  // per-wave [qrow16][t]
    int tid = threadIdx.x;
    int lane = tid & 63, w = tid >> 6;
    int quad = lane >> 4, l15 = lane & 15;
    int s0 = blockIdx.x << 6;
    int h  = blockIdx.y;
    int b  = blockIdx.z;
    int khd = h >> 2;                   // G = 4

    // stage Q tile (64 rows x 64 halves)
    #pragma unroll
    for (int c = tid; c < 512; c += 256) {
        int r = c >> 3, col = (c & 7) << 3;
        *(uint4*)&Qs[r * 72 + col] =
            *(const uint4*)&qh[((size_t)(b * SS + s0 + r)) * HH + h * 64 + col];
    }
    __syncthreads();
    f16x8 qf[2];
    qf[0] = *(const f16x8*)&Qs[(w * 16 + l15) * 72 + quad * 8];
    qf[1] = *(const f16x8*)&Qs[(w * 16 + l15) * 72 + 32 + quad * 8];

    float m[4] = {-INFINITY, -INFINITY, -INFINITY, -INFINITY};
    float l[4] = {0.f, 0.f, 0.f, 0.f};
    f32x4 of[4] = {};

    for (int t0 = 0; t0 <= s0; t0 += 64) {
        __syncthreads();                // prior-iter K/V readers done
        #pragma unroll
        for (int c = tid; c < 512; c += 256) {
            int r = c >> 3, col = (c & 7) << 3;
            *(uint4*)&Ks[r * 72 + col] =
                *(const uint4*)&kh[((size_t)(b * SS + t0 + r)) * (NKV_ * 64) + khd * 64 + col];
            *(uint4*)&Vs[r * 72 + col] =
                *(const uint4*)&vT[(((size_t)(b * NKV_ + khd)) * 64 + r) * SS + t0 + col];
        }
        __syncthreads();

        // S = Q K^T : rows = q (A), cols = t (B)
        f32x4 sa[4] = {};
        #pragma unroll
        for (int j = 0; j < 4; ++j) {
            f16x8 kf0 = *(const f16x8*)&Ks[(j * 16 + l15) * 72 + quad * 8];
            f16x8 kf1 = *(const f16x8*)&Ks[(j * 16 + l15) * 72 + 32 + quad * 8];
            sa[j] = __builtin_amdgcn_mfma_f32_16x16x32_f16(qf[0], kf0, sa[j], 0, 0, 0);
            sa[j] = __builtin_amdgcn_mfma_f32_16x16x32_f16(qf[1], kf1, sa[j], 0, 0, 0);
        }

        if (t0 == s0) {                 // causal mask, diagonal tile only
            #pragma unroll
            for (int j = 0; j < 4; ++j) {
                int t = j * 16 + l15;
                #pragma unroll
                for (int r = 0; r < 4; ++r)
                    if (t > w * 16 + quad * 4 + r) sa[j][r] = -INFINITY;
            }
        }

        // online softmax, rows in C layout (row = quad*4+r, col = j*16+l15)
        #pragma unroll
        for (int r = 0; r < 4; ++r) {
            float rm = fmaxf(fmaxf(sa[0][r], sa[1][r]), fmaxf(sa[2][r], sa[3][r]));
            rm = fmaxf(rm, __shfl_xor(rm, 1, 64));
            rm = fmaxf(rm, __shfl_xor(rm, 2, 64));
            rm = fmaxf(rm, __shfl_xor(rm, 4, 64));
            rm = fmaxf(rm, __shfl_xor(rm, 8, 64));
            float mn = fmaxf(m[r], rm);
            float al = __expf(m[r] - mn);
            float p0 = __expf(sa[0][r] - mn);
            float p1 = __expf(sa[1][r] - mn);
            float p2 = __expf(sa[2][r] - mn);
            float p3 = __expf(sa[3][r] - mn);
            float rs = (p0 + p1) + (p2 + p3);
            rs += __shfl_xor(rs, 1, 64);
            rs += __shfl_xor(rs, 2, 64);
            rs += __shfl_xor(rs, 4, 64);
            rs += __shfl_xor(rs, 8, 64);
            l[r] = l[r] * al + rs;
            m[r] = mn;
            of[0][r] *= al; of[1][r] *= al; of[2][r] *= al; of[3][r] *= al;
            int prow = (quad * 4 + r) * 72 + l15;
            Ps[w][prow]      = f2h(p0);
            Ps[w][prow + 16] = f2h(p1);
            Ps[w][prow + 32] = f2h(p2);
            Ps[w][prow + 48] = f2h(p3);
        }

        // O += P V  (A = P rows=q, B = V^T rows=d); per-wave Ps, no barrier needed
        f16x8 pf0 = *(const f16x8*)&Ps[w][l15 * 72 + quad * 8];
        f16x8 pf1 = *(const f16x8*)&Ps[w][l15 * 72 + 32 + quad * 8];
        #pragma unroll
        for (int j = 0; j < 4; ++j) {
            f16x8 vf0 = *(const f16x8*)&Vs[(j * 16 + l15) * 72 + quad * 8];
            f16x8 vf1 = *(const f16x8*)&Vs[(j * 16 + l15) * 72 + 32 + quad * 8];
            of[j] = __builtin_amdgcn_mfma_f32_16x16x32_f16(pf0, vf0, of[j], 0, 0, 0);
            of[j] = __builtin_amdgcn_mfma_f32_16x16x32_f16(pf1, vf1, of[j], 0, 0, 0);
        }
    }

    #pragma unroll
    for (int r = 0; r < 4; ++r) {
        int row = s0 + w * 16 + quad * 4 + r;
        float inv = 1.f / l[r];
        #pragma unroll
        for (int j = 0; j < 4; ++j)
            attno[((size_t)(b * SS + row)) * HH + h * 64 + j * 16 + l15] = of[j][r] * inv;
    }
}

extern "C" void kernel_launch(void* const* d_in, const int* in_sizes, int n_in,
                              void* d_out, int out_size, void* d_ws, size_t ws_size,
                              hipStream_t stream) {
    const float* x      = (const float*)d_in[0];
    const float* w_norm = (const float*)d_in[1];
    const float* w_qkv  = (const float*)d_in[2];
    const float* w_out  = (const float*)d_in[3];
    float* out = (float*)d_out;
    char* ws = (char*)d_ws;

    float*  scal  = (float*)(ws + 0);           // [0]=sum|w_qkv|, [1]=sum|w_out|
    float*  rope  = (float*)(ws + 64);          // 2048*64 f32
    ushort* xq    = (ushort*)(ws + 524352);     // 4096*2048 bf16
    float*  xsc   = (float*)(ws + 17301568);    // 4096 f32
    ushort* wq1   = (ushort*)(ws + 17317952);   // 3072*2048 bf16
    ushort* wq2   = (ushort*)(ws + 29900864);   // 2048*2048 bf16
    float*  qkv   = (float*)(ws + 38289472);    // 4096*3072 f32
    float*  attno = (float*)(ws + 88621120);    // 4096*2048 f32
    ushort* qh    = (ushort*)(ws + 122175552);  // 4096*2048 f16
    ushort* kh    = (ushort*)(ws + 138952768);  // 4096*512 f16
    ushort* vT    = (ushort*)(ws + 143147072);  // 2*8*64*2048 f16 (ends 147341376)

    hipMemsetAsync(scal, 0, 64, stream);
    absum_kernel<<<2048, 256, 0, stream>>>(w_qkv, scal + 0, QKVO * HH);
    absum_kernel<<<2048, 256, 0, stream>>>(w_out, scal + 1, HH * HH);
    wquant_kernel<<<8192, 256, 0, stream>>>(w_qkv, wq1, scal + 0, 1.0f / 6291456.0f, QKVO * HH);
    wquant_kernel<<<8192, 256, 0, stream>>>(w_out, wq2, scal + 1, 1.0f / 4194304.0f, HH * HH);
    rmsq_kernel<<<MTOK, 256, 0, stream>>>(x, w_norm, xq, xsc);
    gemm_mfma_kernel<<<dim3(QKVO / 128, MTOK / 128), 256, 0, stream>>>(xq, wq1, qkv, xsc, scal + 0,
                                                                       1.0f / 6291456.0f, QKVO, HH);
    rope_table_kernel<<<SS * 32 / 256, 256, 0, stream>>>(rope);
    rope_f16_kernel<<<MTOK * 40 * 32 / 256, 256, 0, stream>>>(qkv, rope, qh, kh);
    vconv_kernel<<<2 * NKV_ * 64 * SS / 256, 256, 0, stream>>>(qkv, vT);
    attn_mfma_kernel<<<dim3(SS / 64, NH_, 2), 256, 0, stream>>>(qh, kh, vT, attno);
    rowq_kernel<<<MTOK, 256, 0, stream>>>(attno, xq, xsc);
    gemm_mfma_kernel<<<dim3(HH / 128, MTOK / 128), 256, 0, stream>>>(xq, wq2, out, xsc, scal + 1,
                                                                     1.0f / 4194304.0f, HH, HH);
}

// Round 6
// 523.793 us; speedup vs baseline: 12.1930x; 1.0673x over previous
//
#include <hip/hip_runtime.h>
#include <math.h>

#define SS   2048
#define HH   2048
#define NH_  32
#define NKV_ 8
#define HD_  64
#define QKVO 3072     // (32 + 2*8) * 64
#define MTOK 4096     // B * S

typedef short bf16x8 __attribute__((ext_vector_type(8)));     // 8 bf16 in 4 VGPRs
typedef _Float16 f16x8 __attribute__((ext_vector_type(8)));   // 8 fp16 in 4 VGPRs
typedef float f32x4 __attribute__((ext_vector_type(4)));

__device__ inline ushort f2bf(float f) {                      // exact for our integer values
    return (ushort)(__float_as_uint(f) >> 16);
}
__device__ inline ushort f2h(float f) {
    _Float16 h = (_Float16)f;
    return *(ushort*)&h;
}

__device__ inline void gl_lds16(const void* g, void* l) {
    __builtin_amdgcn_global_load_lds((const __attribute__((address_space(1))) void*)g,
                                     (__attribute__((address_space(3))) void*)l, 16, 0, 0);
}

// ---------------- sum |w| reduction ----------------
__global__ __launch_bounds__(256) void absum_kernel(const float* __restrict__ w,
                                                    float* __restrict__ out, int n) {
    __shared__ float red[256];
    int tid = threadIdx.x;
    float acc = 0.f;
    for (int i = blockIdx.x * 256 + tid; i < n; i += gridDim.x * 256)
        acc += fabsf(w[i]);
    red[tid] = acc;
    __syncthreads();
    for (int s = 128; s > 0; s >>= 1) {
        if (tid < s) red[tid] += red[tid + s];
        __syncthreads();
    }
    if (tid == 0) atomicAdd(out, red[0]);
}

// ---------------- ternary weight quant -> bf16 ----------------
__global__ __launch_bounds__(256) void wquant_kernel(const float* __restrict__ w,
                                                     ushort* __restrict__ wq,
                                                     const float* __restrict__ sum,
                                                     float inv_n, int n) {
    float mean = fmaxf(sum[0] * inv_n, 1e-5f);
    float wsc = 1.f / mean;
    for (int i = blockIdx.x * 256 + threadIdx.x; i < n; i += gridDim.x * 256) {
        float q = rintf(w[i] * wsc);
        wq[i] = f2bf(fminf(fmaxf(q, -1.f), 1.f));
    }
}

// ---------------- RMSNorm + activation quant -> bf16 (one block per row, H=2048) ----------------
__global__ __launch_bounds__(256) void rmsq_kernel(const float* __restrict__ x,
                                                   const float* __restrict__ wn,
                                                   ushort* __restrict__ xq,
                                                   float* __restrict__ xsc) {
    __shared__ float red[256];
    int tid = threadIdx.x;
    const float* xr = x + (size_t)blockIdx.x * HH;
    float4 a = ((const float4*)xr)[tid];
    float4 b = ((const float4*)xr)[tid + 256];
    float s2 = a.x*a.x + a.y*a.y + a.z*a.z + a.w*a.w
             + b.x*b.x + b.y*b.y + b.z*b.z + b.w*b.w;
    red[tid] = s2;
    __syncthreads();
    for (int s = 128; s > 0; s >>= 1) { if (tid < s) red[tid] += red[tid + s]; __syncthreads(); }
    float r = rsqrtf(red[0] * (1.f / HH) + 1e-5f);
    __syncthreads();
    float4 wa = ((const float4*)wn)[tid];
    float4 wb = ((const float4*)wn)[tid + 256];
    float4 na, nb;
    na.x = a.x * r * wa.x; na.y = a.y * r * wa.y; na.z = a.z * r * wa.z; na.w = a.w * r * wa.w;
    nb.x = b.x * r * wb.x; nb.y = b.y * r * wb.y; nb.z = b.z * r * wb.z; nb.w = b.w * r * wb.w;
    float am = fabsf(na.x);
    am = fmaxf(am, fabsf(na.y)); am = fmaxf(am, fabsf(na.z)); am = fmaxf(am, fabsf(na.w));
    am = fmaxf(am, fabsf(nb.x)); am = fmaxf(am, fabsf(nb.y));
    am = fmaxf(am, fabsf(nb.z)); am = fmaxf(am, fabsf(nb.w));
    red[tid] = am;
    __syncthreads();
    for (int s = 128; s > 0; s >>= 1) { if (tid < s) red[tid] = fmaxf(red[tid], red[tid + s]); __syncthreads(); }
    float amax = fmaxf(red[0], 1e-5f);
    float xs = 127.f / amax;
    if (tid == 0) xsc[blockIdx.x] = amax * (1.f / 127.f);
    ushort* qr = xq + (size_t)blockIdx.x * HH;
    ushort4 ua, ub;
    ua.x = f2bf(fminf(fmaxf(rintf(na.x * xs), -128.f), 127.f));
    ua.y = f2bf(fminf(fmaxf(rintf(na.y * xs), -128.f), 127.f));
    ua.z = f2bf(fminf(fmaxf(rintf(na.z * xs), -128.f), 127.f));
    ua.w = f2bf(fminf(fmaxf(rintf(na.w * xs), -128.f), 127.f));
    ub.x = f2bf(fminf(fmaxf(rintf(nb.x * xs), -128.f), 127.f));
    ub.y = f2bf(fminf(fmaxf(rintf(nb.y * xs), -128.f), 127.f));
    ub.z = f2bf(fminf(fmaxf(rintf(nb.z * xs), -128.f), 127.f));
    ub.w = f2bf(fminf(fmaxf(rintf(nb.w * xs), -128.f), 127.f));
    ((ushort4*)qr)[tid] = ua;
    ((ushort4*)qr)[tid + 256] = ub;
}

// ---------------- row absmax quant -> bf16 (attention output, H=2048) ----------------
__global__ __launch_bounds__(256) void rowq_kernel(const float* __restrict__ x,
                                                   ushort* __restrict__ xq,
                                                   float* __restrict__ xsc) {
    __shared__ float red[256];
    int tid = threadIdx.x;
    const float* xr = x + (size_t)blockIdx.x * HH;
    float4 a = ((const float4*)xr)[tid];
    float4 b = ((const float4*)xr)[tid + 256];
    float am = fabsf(a.x);
    am = fmaxf(am, fabsf(a.y)); am = fmaxf(am, fabsf(a.z)); am = fmaxf(am, fabsf(a.w));
    am = fmaxf(am, fabsf(b.x)); am = fmaxf(am, fabsf(b.y));
    am = fmaxf(am, fabsf(b.z)); am = fmaxf(am, fabsf(b.w));
    red[tid] = am;
    __syncthreads();
    for (int s = 128; s > 0; s >>= 1) { if (tid < s) red[tid] = fmaxf(red[tid], red[tid + s]); __syncthreads(); }
    float amax = fmaxf(red[0], 1e-5f);
    float xs = 127.f / amax;
    if (tid == 0) xsc[blockIdx.x] = amax * (1.f / 127.f);
    ushort* qr = xq + (size_t)blockIdx.x * HH;
    ushort4 ua, ub;
    ua.x = f2bf(fminf(fmaxf(rintf(a.x * xs), -128.f), 127.f));
    ua.y = f2bf(fminf(fmaxf(rintf(a.y * xs), -128.f), 127.f));
    ua.z = f2bf(fminf(fmaxf(rintf(a.z * xs), -128.f), 127.f));
    ua.w = f2bf(fminf(fmaxf(rintf(a.w * xs), -128.f), 127.f));
    ub.x = f2bf(fminf(fmaxf(rintf(b.x * xs), -128.f), 127.f));
    ub.y = f2bf(fminf(fmaxf(rintf(b.y * xs), -128.f), 127.f));
    ub.z = f2bf(fminf(fmaxf(rintf(b.z * xs), -128.f), 127.f));
    ub.w = f2bf(fminf(fmaxf(rintf(b.w * xs), -128.f), 127.f));
    ((ushort4*)qr)[tid] = ua;
    ((ushort4*)qr)[tid + 256] = ub;
}

// ---------------- bf16 MFMA GEMM (m97 structure): C[M,N] = A[M,K]*B[N,K]^T, scaled ----------------
__global__ __launch_bounds__(256) void gemm_mfma_kernel(const ushort* __restrict__ A,
                                                        const ushort* __restrict__ B,
                                                        float* __restrict__ C,
                                                        const float* __restrict__ rsc,
                                                        const float* __restrict__ wsum,
                                                        float inv_n, int N, int K) {
    __shared__ __align__(16) ushort Alds[128 * 32];
    __shared__ __align__(16) ushort Blds[128 * 32];
    int tid = threadIdx.x;
    int lane = tid & 63, w = tid >> 6;
    int quad = lane >> 4, l15 = lane & 15;
    int m0 = blockIdx.y << 7, n0 = blockIdx.x << 7;
    int wm = (w >> 1) << 6, wn = (w & 1) << 6;
    int srow = (w << 5) + (lane >> 2);
    int scol = (lane & 3) << 3;
    const ushort* Arow = A + (size_t)(m0 + srow) * K + scol;
    const ushort* Brow = B + (size_t)(n0 + srow) * K + scol;
    ushort* Adst = &Alds[w << 10];
    ushort* Bdst = &Blds[w << 10];

    f32x4 acc[4][4] = {};
    for (int k0 = 0; k0 < K; k0 += 32) {
        gl_lds16(Arow + k0, Adst);
        gl_lds16(Arow + (size_t)16 * K + k0, Adst + 512);
        gl_lds16(Brow + k0, Bdst);
        gl_lds16(Brow + (size_t)16 * K + k0, Bdst + 512);
        __syncthreads();
        bf16x8 af[4], bfr[4];
        #pragma unroll
        for (int i = 0; i < 4; ++i) {
            af[i]  = *(const bf16x8*)&Alds[(wm + i * 16 + l15) * 32 + quad * 8];
            bfr[i] = *(const bf16x8*)&Blds[(wn + i * 16 + l15) * 32 + quad * 8];
        }
        #pragma unroll
        for (int i = 0; i < 4; ++i)
            #pragma unroll
            for (int j = 0; j < 4; ++j)
                acc[i][j] = __builtin_amdgcn_mfma_f32_16x16x32_bf16(af[i], bfr[j], acc[i][j], 0, 0, 0);
        __syncthreads();
    }

    float wsc = fmaxf(wsum[0] * inv_n, 1e-5f);
    #pragma unroll
    for (int i = 0; i < 4; ++i) {
        #pragma unroll
        for (int r = 0; r < 4; ++r) {
            int row = m0 + wm + i * 16 + quad * 4 + r;
            float s = rsc[row] * wsc;
            #pragma unroll
            for (int j = 0; j < 4; ++j) {
                int col = n0 + wn + j * 16 + l15;
                C[(size_t)row * N + col] = acc[i][j][r] * s;
            }
        }
    }
}

// ---------------- RoPE table ----------------
__global__ __launch_bounds__(256) void rope_table_kernel(float* __restrict__ tab) {
    int i = blockIdx.x * 256 + threadIdx.x;     // S*32 threads
    int sp = i >> 5, d = i & 31;
    float inv = (float)pow(10000.0, -(double)d / 32.0);
    float ang = (float)sp * inv;
    tab[sp * 64 + d]      = cosf(ang);
    tab[sp * 64 + 32 + d] = sinf(ang);
}

// ---------------- RoPE apply -> fp16 q (x0.125) and k side buffers ----------------
__global__ __launch_bounds__(256) void rope_f16_kernel(const float* __restrict__ qkv,
                                                       const float* __restrict__ tab,
                                                       ushort* __restrict__ qh,
                                                       ushort* __restrict__ kh) {
    int i = blockIdx.x * 256 + threadIdx.x;     // MTOK*40*32 threads
    int d = i & 31;
    int hh = (i >> 5) % 40;
    int row = i / 1280;
    int sp = row & (SS - 1);
    size_t base = (size_t)row * QKVO + (hh < 32 ? hh * 64 : HH + (hh - 32) * 64);
    float c = tab[sp * 64 + d], sn = tab[sp * 64 + 32 + d];
    float xr = qkv[base + d], xi = qkv[base + d + 32];
    float ro = xr * c - xi * sn;
    float io = xr * sn + xi * c;
    if (hh < 32) {
        ushort* dst = qh + (size_t)row * HH + hh * 64;
        dst[d]      = f2h(ro * 0.125f);
        dst[d + 32] = f2h(io * 0.125f);
    } else {
        ushort* dst = kh + (size_t)row * (NKV_ * 64) + (hh - 32) * 64;
        dst[d]      = f2h(ro);
        dst[d + 32] = f2h(io);
    }
}

// ---------------- V -> fp16 transposed [b][kv][d][s], LDS-tiled (coalesced) ----------------
__global__ __launch_bounds__(256) void vconv_kernel(const float* __restrict__ qkv,
                                                    ushort* __restrict__ vT) {
    __shared__ float tile[64][65];
    int t0 = (blockIdx.x & 31) << 6;
    int kv = (blockIdx.x >> 5) & 7;
    int b  = blockIdx.x >> 8;
    int tr = threadIdx.x >> 2;
    int dc = (threadIdx.x & 3) << 4;
    const float* src = qkv + ((size_t)(b * SS + t0 + tr)) * QKVO + HH + NKV_ * 64 + kv * 64 + dc;
    #pragma unroll
    for (int k4 = 0; k4 < 4; ++k4) {
        float4 v = *(const float4*)(src + k4 * 4);
        tile[tr][dc + k4 * 4 + 0] = v.x;
        tile[tr][dc + k4 * 4 + 1] = v.y;
        tile[tr][dc + k4 * 4 + 2] = v.z;
        tile[tr][dc + k4 * 4 + 3] = v.w;
    }
    __syncthreads();
    int dr = threadIdx.x >> 2;
    int tc = (threadIdx.x & 3) << 4;
    ushort* dst = vT + (((size_t)(b * NKV_ + kv)) * 64 + dr) * SS + t0 + tc;
    #pragma unroll
    for (int g = 0; g < 4; ++g) {
        ushort4 o;
        o.x = f2h(tile[tc + g * 4 + 0][dr]);
        o.y = f2h(tile[tc + g * 4 + 1][dr]);
        o.z = f2h(tile[tc + g * 4 + 2][dr]);
        o.w = f2h(tile[tc + g * 4 + 3][dr]);
        *(ushort4*)(dst + g * 4) = o;
    }
}

// ---------------- MFMA flash attention (fp16 in, fp32 softmax/accum) ----------------
// grid (32 s-tiles REVERSED: longest work first, 32 heads, 2 b); 4 waves x 16 q-rows.
// All LDS row strides 68 halves (34 dw == 2 mod 32): P-writes & frag reads conflict-free.
// Per-lane partial l, reduced once at end (al is row-uniform) — halves shfl traffic.
__global__ __launch_bounds__(256) void attn_mfma_kernel(const ushort* __restrict__ qh,
                                                        const ushort* __restrict__ kh,
                                                        const ushort* __restrict__ vT,
                                                        float* __restrict__ attno) {
    __shared__ ushort Qs[64 * 68];     // [qrow][d]
    __shared__ ushort Ks[64 * 68];     // [t][d]
    __shared__ ushort Vs[64 * 68];     // [d][t]
    __shared__ ushort Ps[4][16 * 68];  // per-wave [qrow16][t]
    int tid = threadIdx.x;
    int lane = tid & 63, w = tid >> 6;
    int quad = lane >> 4, l15 = lane & 15;
    int s0 = (SS / 64 - 1 - blockIdx.x) << 6;   // longest-first dispatch
    int h  = blockIdx.y;
    int b  = blockIdx.z;
    int khd = h >> 2;                   // G = 4

    #pragma unroll
    for (int c = tid; c < 512; c += 256) {
        int r = c >> 3, col = (c & 7) << 3;
        *(uint4*)&Qs[r * 68 + col] =
            *(const uint4*)&qh[((size_t)(b * SS + s0 + r)) * HH + h * 64 + col];
    }
    __syncthreads();
    f16x8 qf[2];
    qf[0] = *(const f16x8*)&Qs[(w * 16 + l15) * 68 + quad * 8];
    qf[1] = *(const f16x8*)&Qs[(w * 16 + l15) * 68 + 32 + quad * 8];

    float m[4]  = {-INFINITY, -INFINITY, -INFINITY, -INFINITY};
    float lp[4] = {0.f, 0.f, 0.f, 0.f};          // per-lane partial row sums
    f32x4 of[4] = {};

    for (int t0 = 0; t0 <= s0; t0 += 64) {
        __syncthreads();
        #pragma unroll
        for (int c = tid; c < 512; c += 256) {
            int r = c >> 3, col = (c & 7) << 3;
            *(uint4*)&Ks[r * 68 + col] =
                *(const uint4*)&kh[((size_t)(b * SS + t0 + r)) * (NKV_ * 64) + khd * 64 + col];
            *(uint4*)&Vs[r * 68 + col] =
                *(const uint4*)&vT[(((size_t)(b * NKV_ + khd)) * 64 + r) * SS + t0 + col];
        }
        __syncthreads();

        f32x4 sa[4] = {};
        #pragma unroll
        for (int j = 0; j < 4; ++j) {
            f16x8 kf0 = *(const f16x8*)&Ks[(j * 16 + l15) * 68 + quad * 8];
            f16x8 kf1 = *(const f16x8*)&Ks[(j * 16 + l15) * 68 + 32 + quad * 8];
            sa[j] = __builtin_amdgcn_mfma_f32_16x16x32_f16(qf[0], kf0, sa[j], 0, 0, 0);
            sa[j] = __builtin_amdgcn_mfma_f32_16x16x32_f16(qf[1], kf1, sa[j], 0, 0, 0);
        }

        if (t0 == s0) {
            #pragma unroll
            for (int j = 0; j < 4; ++j) {
                int t = j * 16 + l15;
                #pragma unroll
                for (int r = 0; r < 4; ++r)
                    if (t > w * 16 + quad * 4 + r) sa[j][r] = -INFINITY;
            }
        }

        #pragma unroll
        for (int r = 0; r < 4; ++r) {
            float rm = fmaxf(fmaxf(sa[0][r], sa[1][r]), fmaxf(sa[2][r], sa[3][r]));
            rm = fmaxf(rm, __shfl_xor(rm, 1, 64));
            rm = fmaxf(rm, __shfl_xor(rm, 2, 64));
            rm = fmaxf(rm, __shfl_xor(rm, 4, 64));
            rm = fmaxf(rm, __shfl_xor(rm, 8, 64));
            float mn = fmaxf(m[r], rm);
            float al = __expf(m[r] - mn);
            float p0 = __expf(sa[0][r] - mn);
            float p1 = __expf(sa[1][r] - mn);
            float p2 = __expf(sa[2][r] - mn);
            float p3 = __expf(sa[3][r] - mn);
            lp[r] = lp[r] * al + ((p0 + p1) + (p2 + p3));
            m[r] = mn;
            of[0][r] *= al; of[1][r] *= al; of[2][r] *= al; of[3][r] *= al;
            int prow = (quad * 4 + r) * 68 + l15;
            Ps[w][prow]      = f2h(p0);
            Ps[w][prow + 16] = f2h(p1);
            Ps[w][prow + 32] = f2h(p2);
            Ps[w][prow + 48] = f2h(p3);
        }

        f16x8 pf0 = *(const f16x8*)&Ps[w][l15 * 68 + quad * 8];
        f16x8 pf1 = *(const f16x8*)&Ps[w][l15 * 68 + 32 + quad * 8];
        #pragma unroll
        for (int j = 0; j < 4; ++j) {
            f16x8 vf0 = *(const f16x8*)&Vs[(j * 16 + l15) * 68 + quad * 8];
            f16x8 vf1 = *(const f16x8*)&Vs[(j * 16 + l15) * 68 + 32 + quad * 8];
            of[j] = __builtin_amdgcn_mfma_f32_16x16x32_f16(pf0, vf0, of[j], 0, 0, 0);
            of[j] = __builtin_amdgcn_mfma_f32_16x16x32_f16(pf1, vf1, of[j], 0, 0, 0);
        }
    }

    #pragma unroll
    for (int r = 0; r < 4; ++r) {
        float lr = lp[r];
        lr += __shfl_xor(lr, 1, 64);
        lr += __shfl_xor(lr, 2, 64);
        lr += __shfl_xor(lr, 4, 64);
        lr += __shfl_xor(lr, 8, 64);
        int row = s0 + w * 16 + quad * 4 + r;
        float inv = 1.f / lr;
        #pragma unroll
        for (int j = 0; j < 4; ++j)
            attno[((size_t)(b * SS + row)) * HH + h * 64 + j * 16 + l15] = of[j][r] * inv;
    }
}

extern "C" void kernel_launch(void* const* d_in, const int* in_sizes, int n_in,
                              void* d_out, int out_size, void* d_ws, size_t ws_size,
                              hipStream_t stream) {
    const float* x      = (const float*)d_in[0];
    const float* w_norm = (const float*)d_in[1];
    const float* w_qkv  = (const float*)d_in[2];
    const float* w_out  = (const float*)d_in[3];
    float* out = (float*)d_out;
    char* ws = (char*)d_ws;

    float*  scal  = (float*)(ws + 0);           // [0]=sum|w_qkv|, [1]=sum|w_out|
    float*  rope  = (float*)(ws + 64);          // 2048*64 f32
    ushort* xq    = (ushort*)(ws + 524352);     // 4096*2048 bf16
    float*  xsc   = (float*)(ws + 17301568);    // 4096 f32
    ushort* wq1   = (ushort*)(ws + 17317952);   // 3072*2048 bf16
    ushort* wq2   = (ushort*)(ws + 29900864);   // 2048*2048 bf16
    float*  qkv   = (float*)(ws + 38289472);    // 4096*3072 f32
    float*  attno = (float*)(ws + 88621120);    // 4096*2048 f32
    ushort* qh    = (ushort*)(ws + 122175552);  // 4096*2048 f16
    ushort* kh    = (ushort*)(ws + 138952768);  // 4096*512 f16
    ushort* vT    = (ushort*)(ws + 143147072);  // 2*8*64*2048 f16 (ends 147341376)

    hipMemsetAsync(scal, 0, 64, stream);
    absum_kernel<<<2048, 256, 0, stream>>>(w_qkv, scal + 0, QKVO * HH);
    absum_kernel<<<2048, 256, 0, stream>>>(w_out, scal + 1, HH * HH);
    wquant_kernel<<<8192, 256, 0, stream>>>(w_qkv, wq1, scal + 0, 1.0f / 6291456.0f, QKVO * HH);
    wquant_kernel<<<8192, 256, 0, stream>>>(w_out, wq2, scal + 1, 1.0f / 4194304.0f, HH * HH);
    rmsq_kernel<<<MTOK, 256, 0, stream>>>(x, w_norm, xq, xsc);
    gemm_mfma_kernel<<<dim3(QKVO / 128, MTOK / 128), 256, 0, stream>>>(xq, wq1, qkv, xsc, scal + 0,
                                                                       1.0f / 6291456.0f, QKVO, HH);
    rope_table_kernel<<<SS * 32 / 256, 256, 0, stream>>>(rope);
    rope_f16_kernel<<<MTOK * 40 * 32 / 256, 256, 0, stream>>>(qkv, rope, qh, kh);
    vconv_kernel<<<2 * NKV_ * 32, 256, 0, stream>>>(qkv, vT);
    attn_mfma_kernel<<<dim3(SS / 64, NH_, 2), 256, 0, stream>>>(qh, kh, vT, attno);
    rowq_kernel<<<MTOK, 256, 0, stream>>>(attno, xq, xsc);
    gemm_mfma_kernel<<<dim3(HH / 128, MTOK / 128), 256, 0, stream>>>(xq, wq2, out, xsc, scal + 1,
                                                                     1.0f / 4194304.0f, HH, HH);
}